// Round 1
// baseline (486.246 us; speedup 1.0000x reference)
//
#include <hip/hip_runtime.h>
#include <hip/hip_bf16.h>
#include <cstdint>
#include <cstddef>

// ---------------- problem constants ----------------
constexpr int B_  = 2;
constexpr int S_  = 256;
constexpr int CN_ = 256;
constexpr int CE_ = 128;
constexpr int A_  = 32;
constexpr int H_  = 8;
constexpr int V_  = 32;
constexpr int AH_ = A_ * H_;    // 256
constexpr int VH_ = V_ * H_;    // 256
constexpr int SS_ = S_ * S_;    // 65536
constexpr int CNE_ = CN_ + CE_; // 384

// ---------------- workspace layout (float offsets) ----------------
constexpr size_t OFF_N1   = 0;                                  // nodes1 (B,CN,S)
constexpr size_t OFF_Q    = OFF_N1  + (size_t)B_*CN_*S_;        // q * 1/sqrt(A) (B,AH,S)
constexpr size_t OFF_VN   = OFF_Q   + (size_t)B_*AH_*S_;        // vnode (B,VH,S)
constexpr size_t OFF_NF   = OFF_VN  + (size_t)B_*VH_*S_;        // nf (B,VH,S)
constexpr size_t OFF_WNF  = OFF_NF  + (size_t)B_*VH_*S_;        // Wnf (B,CE,S)
constexpr size_t OFF_SE   = OFF_WNF + (size_t)B_*CE_*S_;        // se (B*S, H*CE=1024)
constexpr size_t OFF_WT1  = OFF_SE  + (size_t)B_*S_*1024;       // We1^T [c][o]
constexpr size_t OFF_WT2  = OFF_WT1 + 16384;                    // We2^T [c][o]
constexpr size_t OFF_WTE  = OFF_WT2 + 16384;                    // We[:,256:384]^T [c'][o]
constexpr size_t OFF_MASK = OFF_WTE + 16384;                    // canonical f32 mask (B*S)
// total ~4.66 MB of ws

// ---------------- mask normalization ----------------
// Reference mask is bool; harness byte-layout is ambiguous. First element is
// guaranteed true (lengths[0] == S). Sniff byte pattern:
//   bool bytes:  m[0..3] = 1,1,1,1
//   int32:       m[0..3] = 1,0,0,0
//   float32 1.0: m[0..3] = 0,0,128,63
__global__ void k_mask_norm(const unsigned char* __restrict__ mraw,
                            float* __restrict__ ws)
{
    int t = threadIdx.x; // one block of 512 threads covers B*S
    unsigned char b1 = mraw[1], b2 = mraw[2];
    float mv;
    if (b1 == (unsigned char)1) {
        mv = mraw[t] ? 1.f : 0.f;                       // bool bytes
    } else if (b2 == (unsigned char)128) {
        mv = (((const float*)mraw)[t] != 0.f) ? 1.f : 0.f; // float32
    } else {
        mv = (((const int*)mraw)[t] != 0) ? 1.f : 0.f;  // int32
    }
    ws[OFF_MASK + t] = mv;
}

// ---------------- small weight transposes ----------------
__global__ void k_transpose(const float* __restrict__ We1_,
                            const float* __restrict__ We2_,
                            const float* __restrict__ We_,
                            float* __restrict__ ws)
{
    int idx = blockIdx.x * 256 + threadIdx.x;   // 0..49151
    int m = idx >> 14;
    int r = idx & 16383;
    int c = r >> 7, o = r & 127;                // WT[c*128+o] = W[o][c]
    if (m == 0)      ws[OFF_WT1 + r] = We1_[o*CE_ + c];
    else if (m == 1) ws[OFF_WT2 + r] = We2_[o*CE_ + c];
    else             ws[OFF_WTE + r] = We_[o*CNE_ + CN_ + c];
}

// ---------------- node MLP + q + vnode (fused) ----------------
// Block handles 8 s-columns of one batch. Per-thread = one output channel.
__global__ __launch_bounds__(256)
void k_node_mlp_qv(const float* __restrict__ nodes,
                   const float* __restrict__ Wm1, const float* __restrict__ bm1,
                   const float* __restrict__ Wm2, const float* __restrict__ bm2,
                   const float* __restrict__ an0,
                   const float* __restrict__ Wq,  const float* __restrict__ Wv,
                   float* __restrict__ ws)
{
    __shared__ float xs[CN_ * 8];
    __shared__ float hs[CN_ * 8];
    const int t  = threadIdx.x;
    const int b  = blockIdx.x >> 5;           // 32 blocks per batch
    const int s0 = (blockIdx.x & 31) * 8;

    #pragma unroll
    for (int r = 0; r < 8; ++r) {
        int idx = r*256 + t;
        int c = idx >> 3, s = idx & 7;
        xs[c*8+s] = nodes[((size_t)(b*CN_+c))*S_ + s0 + s];
    }
    __syncthreads();

    float acc[8];
    { // layer 1
        float bv = bm1[t];
        #pragma unroll
        for (int s = 0; s < 8; ++s) acc[s] = bv;
        for (int c = 0; c < CN_; ++c) {
            float w = Wm1[t*CN_ + c];
            #pragma unroll
            for (int s = 0; s < 8; ++s) acc[s] = fmaf(w, xs[c*8+s], acc[s]);
        }
        #pragma unroll
        for (int s = 0; s < 8; ++s) hs[t*8+s] = fmaxf(acc[s], 0.f);
    }
    __syncthreads();
    { // layer 2
        float bv = bm2[t];
        #pragma unroll
        for (int s = 0; s < 8; ++s) acc[s] = bv;
        for (int c = 0; c < CN_; ++c) {
            float w = Wm2[t*CN_ + c];
            #pragma unroll
            for (int s = 0; s < 8; ++s) acc[s] = fmaf(w, hs[c*8+s], acc[s]);
        }
    }
    // ReZero residual; overwrite own xs row with nodes1 (no other thread reads it now)
    float a0 = an0[t];
    #pragma unroll
    for (int s = 0; s < 8; ++s) {
        float n1 = xs[t*8+s] + a0 * fmaxf(acc[s], 0.f);
        xs[t*8+s] = n1;
        ws[OFF_N1 + ((size_t)(b*CN_+t))*S_ + s0 + s] = n1;
    }
    __syncthreads();

    { // q (with 1/sqrt(A) folded in)
        #pragma unroll
        for (int s = 0; s < 8; ++s) acc[s] = 0.f;
        for (int c = 0; c < CN_; ++c) {
            float w = Wq[t*CN_ + c];
            #pragma unroll
            for (int s = 0; s < 8; ++s) acc[s] = fmaf(w, xs[c*8+s], acc[s]);
        }
        const float rsA = 0.1767766952966369f; // 1/sqrt(32)
        #pragma unroll
        for (int s = 0; s < 8; ++s)
            ws[OFF_Q + ((size_t)(b*AH_+t))*S_ + s0 + s] = acc[s] * rsA;
    }
    { // vnode = Wv[:, :CN] @ nodes1
        #pragma unroll
        for (int s = 0; s < 8; ++s) acc[s] = 0.f;
        for (int c = 0; c < CN_; ++c) {
            float w = Wv[t*CNE_ + c];
            #pragma unroll
            for (int s = 0; s < 8; ++s) acc[s] = fmaf(w, xs[c*8+s], acc[s]);
        }
        #pragma unroll
        for (int s = 0; s < 8; ++s)
            ws[OFF_VN + ((size_t)(b*VH_+t))*S_ + s0 + s] = acc[s];
    }
}

// ---------------- edge MLP: edges1 = edges + ae0*relu(We2@relu(We1@edges+b1)+b2) ----------------
// Block = one (b, i, 128-wide j tile). Xs[c][j] 64 KiB LDS; 8x8 register micro-tiles.
__global__ __launch_bounds__(256)
void k_edge_mlp(const float* __restrict__ edges,
                const float* __restrict__ ws,
                const float* __restrict__ be1, const float* __restrict__ be2,
                const float* __restrict__ ae0,
                float* __restrict__ e1out)
{
    __shared__ float Xs[CE_ * 128];
    const int t   = threadIdx.x;
    const int blk = blockIdx.x;
    const int b   = blk >> 9;
    const int i   = (blk & 511) >> 1;
    const int j0  = (blk & 1) * 128;
    const float* __restrict__ WT1 = ws + OFF_WT1;
    const float* __restrict__ WT2 = ws + OFF_WT2;
    const float* Ebase = edges + ((size_t)(b*CE_)*S_ + i)*S_ + j0;

    #pragma unroll 8
    for (int r = 0; r < 64; ++r) {
        int idx = r*256 + t;
        int c = idx >> 7, j = idx & 127;
        Xs[c*128 + j] = Ebase[(size_t)c*SS_ + j];
    }
    __syncthreads();

    const int to = t >> 4, tx = t & 15; // o = to*8.., j = tx*8..
    float acc[64];
    { // layer 1
        #pragma unroll
        for (int oo = 0; oo < 8; ++oo) {
            float bb = be1[to*8 + oo];
            #pragma unroll
            for (int jj = 0; jj < 8; ++jj) acc[oo*8+jj] = bb;
        }
        for (int c = 0; c < CE_; ++c) {
            float4 w0 = *(const float4*)(WT1 + c*128 + to*8);
            float4 w1 = *(const float4*)(WT1 + c*128 + to*8 + 4);
            float4 x0 = *(const float4*)(Xs  + c*128 + tx*8);
            float4 x1 = *(const float4*)(Xs  + c*128 + tx*8 + 4);
            float w[8] = {w0.x,w0.y,w0.z,w0.w,w1.x,w1.y,w1.z,w1.w};
            float x[8] = {x0.x,x0.y,x0.z,x0.w,x1.x,x1.y,x1.z,x1.w};
            #pragma unroll
            for (int oo = 0; oo < 8; ++oo)
                #pragma unroll
                for (int jj = 0; jj < 8; ++jj)
                    acc[oo*8+jj] = fmaf(w[oo], x[jj], acc[oo*8+jj]);
        }
        #pragma unroll
        for (int k = 0; k < 64; ++k) acc[k] = fmaxf(acc[k], 0.f);
    }
    __syncthreads(); // all Xs reads complete
    #pragma unroll
    for (int oo = 0; oo < 8; ++oo)
        #pragma unroll
        for (int jj = 0; jj < 8; ++jj)
            Xs[(to*8+oo)*128 + tx*8 + jj] = acc[oo*8+jj]; // G -> Xs
    __syncthreads();

    float acc2[64];
    { // layer 2
        #pragma unroll
        for (int oo = 0; oo < 8; ++oo) {
            float bb = be2[to*8 + oo];
            #pragma unroll
            for (int jj = 0; jj < 8; ++jj) acc2[oo*8+jj] = bb;
        }
        for (int c = 0; c < CE_; ++c) {
            float4 w0 = *(const float4*)(WT2 + c*128 + to*8);
            float4 w1 = *(const float4*)(WT2 + c*128 + to*8 + 4);
            float4 x0 = *(const float4*)(Xs  + c*128 + tx*8);
            float4 x1 = *(const float4*)(Xs  + c*128 + tx*8 + 4);
            float w[8] = {w0.x,w0.y,w0.z,w0.w,w1.x,w1.y,w1.z,w1.w};
            float x[8] = {x0.x,x0.y,x0.z,x0.w,x1.x,x1.y,x1.z,x1.w};
            #pragma unroll
            for (int oo = 0; oo < 8; ++oo)
                #pragma unroll
                for (int jj = 0; jj < 8; ++jj)
                    acc2[oo*8+jj] = fmaf(w[oo], x[jj], acc2[oo*8+jj]);
        }
    }
    // epilogue: re-read original edges (L2-hot), ReZero residual, store edges1
    #pragma unroll
    for (int oo = 0; oo < 8; ++oo) {
        int o = to*8 + oo;
        float a0 = ae0[o];
        const float4* ein  = (const float4*)(Ebase + (size_t)o*SS_ + tx*8);
        float4* eout = (float4*)(e1out + ((size_t)(b*CE_+o)*S_ + i)*S_ + j0 + tx*8);
        float4 e0 = ein[0], e1v = ein[1];
        float4 r0, r1;
        r0.x = e0.x + a0*fmaxf(acc2[oo*8+0], 0.f);
        r0.y = e0.y + a0*fmaxf(acc2[oo*8+1], 0.f);
        r0.z = e0.z + a0*fmaxf(acc2[oo*8+2], 0.f);
        r0.w = e0.w + a0*fmaxf(acc2[oo*8+3], 0.f);
        r1.x = e1v.x + a0*fmaxf(acc2[oo*8+4], 0.f);
        r1.y = e1v.y + a0*fmaxf(acc2[oo*8+5], 0.f);
        r1.z = e1v.z + a0*fmaxf(acc2[oo*8+6], 0.f);
        r1.w = e1v.w + a0*fmaxf(acc2[oo*8+7], 0.f);
        eout[0] = r0; eout[1] = r1;
    }
}

// ---------------- fused attention row kernel ----------------
// Block = one (b, i). qw = (q . Wk_edge) -> sim (CE-dot) -> masked softmax -> se.
// Node part of k is constant per row -> cancels in softmax (skipped entirely).
__global__ __launch_bounds__(256)
void k_attn(const float* __restrict__ e1, float* __restrict__ ws,
            const float* __restrict__ Wk)
{
    __shared__ float qcol[AH_];
    __shared__ float qw[CE_ * 8];      // [c'][h]
    __shared__ float simL[H_ * S_];    // 8 x 256
    __shared__ float Etile[CE_ * 65];  // padded (+1 row stride over 64)
    const int t = threadIdx.x;
    const int b = blockIdx.x >> 8, i = blockIdx.x & 255;
    const float* maskf = ws + OFF_MASK;

    qcol[t] = ws[OFF_Q + ((size_t)(b*AH_+t))*S_ + i];
    __syncthreads();
    #pragma unroll
    for (int k = 0; k < 4; ++k) {      // 1024 qw outputs
        int idx = k*256 + t;
        int c = idx >> 3, h = idx & 7;
        float a = 0.f;
        #pragma unroll
        for (int aa = 0; aa < A_; ++aa)
            a = fmaf(qcol[h*A_ + aa], Wk[(h*A_+aa)*CNE_ + CN_ + c], a);
        qw[c*8 + h] = a;
    }
    __syncthreads();

    // sim row: thread = column j
    const float* Eb = e1 + ((size_t)(b*CE_)*S_ + i)*S_;
    float sv[8];
    #pragma unroll
    for (int h = 0; h < 8; ++h) sv[h] = 0.f;
    for (int c = 0; c < CE_; ++c) {
        float e = Eb[(size_t)c*SS_ + t];
        float4 q0 = *(const float4*)(qw + c*8);
        float4 q1 = *(const float4*)(qw + c*8 + 4);
        sv[0] = fmaf(q0.x, e, sv[0]); sv[1] = fmaf(q0.y, e, sv[1]);
        sv[2] = fmaf(q0.z, e, sv[2]); sv[3] = fmaf(q0.w, e, sv[3]);
        sv[4] = fmaf(q1.x, e, sv[4]); sv[5] = fmaf(q1.y, e, sv[5]);
        sv[6] = fmaf(q1.z, e, sv[6]); sv[7] = fmaf(q1.w, e, sv[7]);
    }
    const bool mj = maskf[b*S_ + t] != 0.f;
    #pragma unroll
    for (int h = 0; h < 8; ++h) simL[h*S_ + t] = mj ? sv[h] : -1e9f;
    __syncthreads();

    { // masked softmax per (h): 32 lanes x 8 strided entries
        const int h = t >> 5, l = t & 31;
        float vv[8]; float m = -3.4e38f;
        #pragma unroll
        for (int k = 0; k < 8; ++k) { vv[k] = simL[h*S_ + l + k*32]; m = fmaxf(m, vv[k]); }
        #pragma unroll
        for (int off = 16; off >= 1; off >>= 1) m = fmaxf(m, __shfl_xor(m, off, 32));
        float ssum = 0.f; float ex[8];
        #pragma unroll
        for (int k = 0; k < 8; ++k) { ex[k] = __expf(vv[k] - m); ssum += ex[k]; }
        #pragma unroll
        for (int off = 16; off >= 1; off >>= 1) ssum += __shfl_xor(ssum, off, 32);
        const float mi = maskf[b*S_ + i];
        const float rr = mi / ssum;     // folds the mm row-mask in
        #pragma unroll
        for (int k = 0; k < 8; ++k) simL[h*S_ + l + k*32] = ex[k] * rr;
    }
    __syncthreads();

    // se[h][c'] = sum_j sim[h][j] * E1[c'][i][j]  (E1 re-read is L2-hot)
    const int cp = t & 127, hg = t >> 7;
    float a4[4] = {0.f, 0.f, 0.f, 0.f};
    for (int jt = 0; jt < 4; ++jt) {
        #pragma unroll 4
        for (int r = 0; r < 32; ++r) {
            int idx = r*256 + t;
            int c = idx >> 6, j = idx & 63;
            Etile[c*65 + j] = Eb[(size_t)c*SS_ + jt*64 + j];
        }
        __syncthreads();
        for (int j = 0; j < 64; ++j) {
            float e = Etile[cp*65 + j];
            #pragma unroll
            for (int k = 0; k < 4; ++k)
                a4[k] = fmaf(e, simL[(hg*4+k)*S_ + jt*64 + j], a4[k]);
        }
        __syncthreads();
    }
    float* se = ws + OFF_SE + (size_t)(b*S_ + i)*1024;
    #pragma unroll
    for (int k = 0; k < 4; ++k) se[(hg*4+k)*128 + cp] = a4[k];
}

// ---------------- nf = vnode*mask_i + Wv_edge @ se ----------------
__global__ __launch_bounds__(256)
void k_nf(float* __restrict__ ws, const float* __restrict__ Wv)
{
    __shared__ float seL[1024];
    const int t = threadIdx.x;
    const int b = blockIdx.x >> 8, i = blockIdx.x & 255;
    const float* se = ws + OFF_SE + (size_t)(b*S_ + i)*1024;
    #pragma unroll
    for (int k = 0; k < 4; ++k) seL[k*256 + t] = se[k*256 + t];
    __syncthreads();
    const int h = t >> 5;
    float acc = 0.f;
    for (int c = 0; c < CE_; ++c)
        acc = fmaf(Wv[t*CNE_ + CN_ + c], seL[h*128 + c], acc);
    const float mi = ws[OFF_MASK + b*S_ + i];
    float nfv = ws[OFF_VN + ((size_t)(b*VH_+t))*S_ + i] * mi + acc;
    ws[OFF_NF + ((size_t)(b*VH_+t))*S_ + i] = nfv;
}

// ---------------- node output + Wnf ----------------
__global__ __launch_bounds__(256)
void k_node_out(float* __restrict__ ws, const float* __restrict__ Wo,
                const float* __restrict__ We, const float* __restrict__ an1,
                float* __restrict__ out_nodes)
{
    __shared__ float xs[VH_ * 8];
    const int t  = threadIdx.x;
    const int b  = blockIdx.x >> 5;
    const int s0 = (blockIdx.x & 31) * 8;
    #pragma unroll
    for (int r = 0; r < 8; ++r) {
        int idx = r*256 + t; int c = idx >> 3, s = idx & 7;
        xs[c*8+s] = ws[OFF_NF + ((size_t)(b*VH_+c))*S_ + s0 + s];
    }
    __syncthreads();
    float acc[8] = {0,0,0,0,0,0,0,0};
    for (int c = 0; c < VH_; ++c) {
        float w = Wo[t*VH_ + c];
        #pragma unroll
        for (int s = 0; s < 8; ++s) acc[s] = fmaf(w, xs[c*8+s], acc[s]);
    }
    float a1 = an1[t];
    #pragma unroll
    for (int s = 0; s < 8; ++s) {
        float mi = ws[OFF_MASK + b*S_ + s0 + s];
        out_nodes[((size_t)(b*CN_+t))*S_ + s0 + s] =
            (ws[OFF_N1 + ((size_t)(b*CN_+t))*S_ + s0 + s] + a1*acc[s]) * mi;
    }
    if (t < CE_) { // Wnf = We[:, :VH] @ nf (feeds edge_att's ef term)
        float acc2[8] = {0,0,0,0,0,0,0,0};
        for (int c = 0; c < VH_; ++c) {
            float w = We[t*CNE_ + c];
            #pragma unroll
            for (int s = 0; s < 8; ++s) acc2[s] = fmaf(w, xs[c*8+s], acc2[s]);
        }
        #pragma unroll
        for (int s = 0; s < 8; ++s)
            ws[OFF_WNF + ((size_t)(b*CE_+t))*S_ + s0 + s] = acc2[s];
    }
}

// ---------------- edge output (in-place on d_out edge region) ----------------
// edge_att = 0.5*(Wnf_i + Wnf_j) + We_edge @ edges1 ; out = (edges1 + ae1*att)*mm
__global__ __launch_bounds__(256)
void k_edge_out(float* __restrict__ e1, const float* __restrict__ ws,
                const float* __restrict__ ae1)
{
    __shared__ float Xs[CE_ * 128];
    const int t   = threadIdx.x;
    const int blk = blockIdx.x;
    const int b   = blk >> 9;
    const int i   = (blk & 511) >> 1;
    const int j0  = (blk & 1) * 128;
    float* Eb = e1 + ((size_t)(b*CE_)*S_ + i)*S_ + j0;

    #pragma unroll 8
    for (int r = 0; r < 64; ++r) {
        int idx = r*256 + t;
        int c = idx >> 7, j = idx & 127;
        Xs[c*128 + j] = Eb[(size_t)c*SS_ + j];
    }
    __syncthreads();

    const int to = t >> 4, tx = t & 15;
    const float* __restrict__ WTe = ws + OFF_WTE;
    float acc[64];
    #pragma unroll
    for (int k = 0; k < 64; ++k) acc[k] = 0.f;
    for (int c = 0; c < CE_; ++c) {
        float4 w0 = *(const float4*)(WTe + c*128 + to*8);
        float4 w1 = *(const float4*)(WTe + c*128 + to*8 + 4);
        float4 x0 = *(const float4*)(Xs  + c*128 + tx*8);
        float4 x1 = *(const float4*)(Xs  + c*128 + tx*8 + 4);
        float w[8] = {w0.x,w0.y,w0.z,w0.w,w1.x,w1.y,w1.z,w1.w};
        float x[8] = {x0.x,x0.y,x0.z,x0.w,x1.x,x1.y,x1.z,x1.w};
        #pragma unroll
        for (int oo = 0; oo < 8; ++oo)
            #pragma unroll
            for (int jj = 0; jj < 8; ++jj)
                acc[oo*8+jj] = fmaf(w[oo], x[jj], acc[oo*8+jj]);
    }

    const float* Wnf = ws + OFF_WNF;
    const float* maskf = ws + OFF_MASK;
    const float mi = maskf[b*S_ + i];
    float mj[8];
    #pragma unroll
    for (int jj = 0; jj < 8; ++jj) mj[jj] = maskf[b*S_ + j0 + tx*8 + jj];
    #pragma unroll
    for (int oo = 0; oo < 8; ++oo) {
        int o = to*8 + oo;
        float a1 = ae1[o];
        float wni = Wnf[(size_t)(b*CE_+o)*S_ + i];
        const float* wnj = Wnf + (size_t)(b*CE_+o)*S_ + j0 + tx*8;
        float* eo = Eb + (size_t)o*SS_ + tx*8;
        float vals[8];
        #pragma unroll
        for (int jj = 0; jj < 8; ++jj) {
            float att = 0.5f*(wni + wnj[jj]) + acc[oo*8+jj];
            vals[jj] = (Xs[o*128 + tx*8 + jj] + a1*att) * (mi * mj[jj]);
        }
        ((float4*)eo)[0] = make_float4(vals[0], vals[1], vals[2], vals[3]);
        ((float4*)eo)[1] = make_float4(vals[4], vals[5], vals[6], vals[7]);
    }
}

// ---------------- launch ----------------
extern "C" void kernel_launch(void* const* d_in, const int* in_sizes, int n_in,
                              void* d_out, int out_size, void* d_ws, size_t ws_size,
                              hipStream_t stream)
{
    const float* nodes = (const float*)d_in[0];
    const float* edges = (const float*)d_in[1];
    const unsigned char* mraw = (const unsigned char*)d_in[2];
    const float* Wq  = (const float*)d_in[3];
    const float* Wk  = (const float*)d_in[4];
    const float* Wv  = (const float*)d_in[5];
    const float* Wo  = (const float*)d_in[6];
    const float* We  = (const float*)d_in[7];
    const float* Wm1 = (const float*)d_in[8];
    const float* bm1 = (const float*)d_in[9];
    const float* Wm2 = (const float*)d_in[10];
    const float* bm2 = (const float*)d_in[11];
    const float* We1 = (const float*)d_in[12];
    const float* be1 = (const float*)d_in[13];
    const float* We2 = (const float*)d_in[14];
    const float* be2 = (const float*)d_in[15];
    const float* an0 = (const float*)d_in[16];
    const float* an1 = (const float*)d_in[17];
    const float* ae0 = (const float*)d_in[18];
    const float* ae1 = (const float*)d_in[19];

    float* ws = (float*)d_ws;
    float* out_nodes = (float*)d_out;
    float* out_edges = out_nodes + (size_t)B_*CN_*S_; // edges1 lives here, updated in-place

    k_mask_norm  <<<1,    512, 0, stream>>>(mraw, ws);
    k_transpose  <<<192,  256, 0, stream>>>(We1, We2, We, ws);
    k_node_mlp_qv<<<64,   256, 0, stream>>>(nodes, Wm1, bm1, Wm2, bm2, an0, Wq, Wv, ws);
    k_edge_mlp   <<<1024, 256, 0, stream>>>(edges, ws, be1, be2, ae0, out_edges);
    k_attn       <<<512,  256, 0, stream>>>(out_edges, ws, Wk);
    k_nf         <<<512,  256, 0, stream>>>(ws, Wv);
    k_node_out   <<<64,   256, 0, stream>>>(ws, Wo, We, an1, out_nodes);
    k_edge_out   <<<1024, 256, 0, stream>>>(out_edges, ws, ae1);
}

// Round 3
// 329.632 us; speedup vs baseline: 1.4751x; 1.4751x over previous
//
#include <hip/hip_runtime.h>
#include <hip/hip_bf16.h>
#include <cstdint>
#include <cstddef>

// ---------------- problem constants ----------------
constexpr int B_  = 2;
constexpr int S_  = 256;
constexpr int CN_ = 256;
constexpr int CE_ = 128;
constexpr int A_  = 32;
constexpr int H_  = 8;
constexpr int V_  = 32;
constexpr int AH_ = A_ * H_;    // 256
constexpr int VH_ = V_ * H_;    // 256
constexpr int SS_ = S_ * S_;    // 65536
constexpr int CNE_ = CN_ + CE_; // 384

// ---------------- workspace layout (float offsets) ----------------
constexpr size_t OFF_N1   = 0;                                  // nodes1 (B,CN,S)
constexpr size_t OFF_Q    = OFF_N1  + (size_t)B_*CN_*S_;        // q * 1/sqrt(A) (B,AH,S)
constexpr size_t OFF_VN   = OFF_Q   + (size_t)B_*AH_*S_;        // vnode (B,VH,S)
constexpr size_t OFF_NF   = OFF_VN  + (size_t)B_*VH_*S_;        // nf (B,VH,S)
constexpr size_t OFF_WNF  = OFF_NF  + (size_t)B_*VH_*S_;        // Wnf (B,CE,S)
constexpr size_t OFF_SE   = OFF_WNF + (size_t)B_*CE_*S_;        // se (B*S, H*CE=1024)
constexpr size_t OFF_WB1  = OFF_SE  + (size_t)B_*S_*1024;       // We1 bf16 [o][c] (as ushort)
constexpr size_t OFF_WB2  = OFF_WB1 + 16384;                    // We2 bf16 [o][c]
constexpr size_t OFF_WBE  = OFF_WB2 + 16384;                    // We[:,256:384] bf16 [o][c]
constexpr size_t OFF_MASK = OFF_WBE + 16384;                    // canonical f32 mask (B*S)

// ---------------- bf16 helpers ----------------
__device__ inline uint16_t f2bf(float x) {
    uint32_t u = __float_as_uint(x);
    uint32_t r = (u + 0x7fffu + ((u >> 16) & 1u)) >> 16;  // RNE
    return (uint16_t)r;
}
__device__ inline float bf2f(uint16_t h) {
    return __uint_as_float(((uint32_t)h) << 16);
}

typedef __attribute__((ext_vector_type(8))) short sh8;
typedef __attribute__((ext_vector_type(4))) short sh4;
typedef __attribute__((ext_vector_type(4))) float f32x4;

#define MFMA_B16(a, b, c) __builtin_amdgcn_mfma_f32_16x16x32_bf16((a), (b), (c), 0, 0, 0)

// LDS tile geometry: [j][c] bf16, row stride 136 ushorts (272B, 17*16B: pad kills
// pow2 stride), plus XOR-swizzle of ushort-index bits 3..5 by (j>>3)&7 so the
// 4-j-per-lane staging writes and the 16-row fragment reads spread banks.
__device__ inline int eidx(int j, int c) {
    return (j * 136 + c) ^ (((j >> 3) & 7) << 3);
}

// ---------------- mask normalization ----------------
__global__ void k_mask_norm(const unsigned char* __restrict__ mraw,
                            float* __restrict__ ws)
{
    int t = threadIdx.x; // one block of 512 threads covers B*S
    unsigned char b1 = mraw[1], b2 = mraw[2];
    float mv;
    if (b1 == (unsigned char)1) {
        mv = mraw[t] ? 1.f : 0.f;                       // bool bytes
    } else if (b2 == (unsigned char)128) {
        mv = (((const float*)mraw)[t] != 0.f) ? 1.f : 0.f; // float32
    } else {
        mv = (((const int*)mraw)[t] != 0) ? 1.f : 0.f;  // int32
    }
    ws[OFF_MASK + t] = mv;
}

// ---------------- weight prep: f32 -> bf16 (natural [o][c] layout for A-frags) ----------------
__global__ void k_wprep(const float* __restrict__ We1_,
                        const float* __restrict__ We2_,
                        const float* __restrict__ We_,
                        float* __restrict__ ws)
{
    int idx = blockIdx.x * 256 + threadIdx.x;   // 0..49151
    int m = idx >> 14;
    int r = idx & 16383;
    int o = r >> 7, c = r & 127;
    ushort* wb1 = (ushort*)(ws + OFF_WB1);
    ushort* wb2 = (ushort*)(ws + OFF_WB2);
    ushort* wbe = (ushort*)(ws + OFF_WBE);
    if (m == 0)      wb1[r] = f2bf(We1_[o*CE_ + c]);
    else if (m == 1) wb2[r] = f2bf(We2_[o*CE_ + c]);
    else             wbe[r] = f2bf(We_[o*CNE_ + CN_ + c]);
}

// ---------------- node MLP + q + vnode (fused) ----------------
__global__ __launch_bounds__(256)
void k_node_mlp_qv(const float* __restrict__ nodes,
                   const float* __restrict__ Wm1, const float* __restrict__ bm1,
                   const float* __restrict__ Wm2, const float* __restrict__ bm2,
                   const float* __restrict__ an0,
                   const float* __restrict__ Wq,  const float* __restrict__ Wv,
                   float* __restrict__ ws)
{
    __shared__ float xs[CN_ * 8];
    __shared__ float hs[CN_ * 8];
    const int t  = threadIdx.x;
    const int b  = blockIdx.x >> 5;           // 32 blocks per batch
    const int s0 = (blockIdx.x & 31) * 8;

    #pragma unroll
    for (int r = 0; r < 8; ++r) {
        int idx = r*256 + t;
        int c = idx >> 3, s = idx & 7;
        xs[c*8+s] = nodes[((size_t)(b*CN_+c))*S_ + s0 + s];
    }
    __syncthreads();

    float acc[8];
    { // layer 1
        float bv = bm1[t];
        #pragma unroll
        for (int s = 0; s < 8; ++s) acc[s] = bv;
        for (int c = 0; c < CN_; ++c) {
            float w = Wm1[t*CN_ + c];
            #pragma unroll
            for (int s = 0; s < 8; ++s) acc[s] = fmaf(w, xs[c*8+s], acc[s]);
        }
        #pragma unroll
        for (int s = 0; s < 8; ++s) hs[t*8+s] = fmaxf(acc[s], 0.f);
    }
    __syncthreads();
    { // layer 2
        float bv = bm2[t];
        #pragma unroll
        for (int s = 0; s < 8; ++s) acc[s] = bv;
        for (int c = 0; c < CN_; ++c) {
            float w = Wm2[t*CN_ + c];
            #pragma unroll
            for (int s = 0; s < 8; ++s) acc[s] = fmaf(w, hs[c*8+s], acc[s]);
        }
    }
    float a0 = an0[t];
    #pragma unroll
    for (int s = 0; s < 8; ++s) {
        float n1 = xs[t*8+s] + a0 * fmaxf(acc[s], 0.f);
        xs[t*8+s] = n1;
        ws[OFF_N1 + ((size_t)(b*CN_+t))*S_ + s0 + s] = n1;
    }
    __syncthreads();

    { // q (with 1/sqrt(A) folded in)
        #pragma unroll
        for (int s = 0; s < 8; ++s) acc[s] = 0.f;
        for (int c = 0; c < CN_; ++c) {
            float w = Wq[t*CN_ + c];
            #pragma unroll
            for (int s = 0; s < 8; ++s) acc[s] = fmaf(w, xs[c*8+s], acc[s]);
        }
        const float rsA = 0.1767766952966369f; // 1/sqrt(32)
        #pragma unroll
        for (int s = 0; s < 8; ++s)
            ws[OFF_Q + ((size_t)(b*AH_+t))*S_ + s0 + s] = acc[s] * rsA;
    }
    { // vnode = Wv[:, :CN] @ nodes1
        #pragma unroll
        for (int s = 0; s < 8; ++s) acc[s] = 0.f;
        for (int c = 0; c < CN_; ++c) {
            float w = Wv[t*CNE_ + c];
            #pragma unroll
            for (int s = 0; s < 8; ++s) acc[s] = fmaf(w, xs[c*8+s], acc[s]);
        }
        #pragma unroll
        for (int s = 0; s < 8; ++s)
            ws[OFF_VN + ((size_t)(b*VH_+t))*S_ + s0 + s] = acc[s];
    }
}

// ---------------- edge MLP via split-bf16 MFMA ----------------
// Block = (b, i, 64-j tile). Waves: 4 x (32 out-rows x 64 j).
// E staged transposed [j][c] as bf16 hi/lo; residual reconstructed as hi+lo.
__global__ __launch_bounds__(256, 2)
void k_edge_mlp(const float* __restrict__ edges,
                const float* __restrict__ ws,
                const float* __restrict__ be1, const float* __restrict__ be2,
                const float* __restrict__ ae0,
                float* __restrict__ e1out)
{
    __shared__ ushort Ehi[64 * 136];
    __shared__ ushort Elo[64 * 136];
    __shared__ ushort Ht [64 * 136];

    const int t  = threadIdx.x;
    const int b  = blockIdx.x >> 10;
    const int i  = (blockIdx.x >> 2) & 255;
    const int j0 = (blockIdx.x & 3) * 64;
    const float* Eb = edges + (size_t)b*CE_*SS_ + (size_t)i*S_ + j0;

    // ---- stage: load f32, split hi/lo bf16, write transposed ----
    {
        const int tj = t & 15;       // j-quad
        const int p0 = t >> 4;       // c-pair
        #pragma unroll
        for (int s = 0; s < 4; ++s) {
            int c = (s*16 + p0) * 2;
            float4 v0 = *(const float4*)(Eb + (size_t)c*SS_ + tj*4);
            float4 v1 = *(const float4*)(Eb + (size_t)(c+1)*SS_ + tj*4);
            float a0[4] = {v0.x, v0.y, v0.z, v0.w};
            float a1[4] = {v1.x, v1.y, v1.z, v1.w};
            #pragma unroll
            for (int jj = 0; jj < 4; ++jj) {
                int j = tj*4 + jj;
                uint16_t h0 = f2bf(a0[jj]); uint16_t l0 = f2bf(a0[jj] - bf2f(h0));
                uint16_t h1 = f2bf(a1[jj]); uint16_t l1 = f2bf(a1[jj] - bf2f(h1));
                int us = eidx(j, c);
                *(uint32_t*)&Ehi[us] = (uint32_t)h0 | ((uint32_t)h1 << 16);
                *(uint32_t*)&Elo[us] = (uint32_t)l0 | ((uint32_t)l1 << 16);
            }
        }
    }

    // ---- preload A fragments (weights bf16, registers) ----
    const int w  = t >> 6;
    const int l  = t & 63;
    const int lr = l & 15;       // row-in-16 / col-in-16
    const int lk = l >> 4;       // k-group
    const ushort* wb1 = (const ushort*)(ws + OFF_WB1);
    const ushort* wb2 = (const ushort*)(ws + OFF_WB2);
    sh8 A1[2][4], A2[2][4];
    #pragma unroll
    for (int mt = 0; mt < 2; ++mt) {
        int o = w*32 + mt*16 + lr;
        #pragma unroll
        for (int ks = 0; ks < 4; ++ks) {
            A1[mt][ks] = *(const sh8*)(wb1 + o*CE_ + ks*32 + lk*8);
            A2[mt][ks] = *(const sh8*)(wb2 + o*CE_ + ks*32 + lk*8);
        }
    }

    // ---- layer 1: acc = be1 + W1*(Ehi+Elo) ----
    f32x4 acc1[2][4];
    #pragma unroll
    for (int mt = 0; mt < 2; ++mt) {
        float4 bv = *(const float4*)(be1 + w*32 + mt*16 + lk*4);
        #pragma unroll
        for (int nt = 0; nt < 4; ++nt) {
            acc1[mt][nt][0] = bv.x; acc1[mt][nt][1] = bv.y;
            acc1[mt][nt][2] = bv.z; acc1[mt][nt][3] = bv.w;
        }
    }
    __syncthreads();
    #pragma unroll
    for (int nt = 0; nt < 4; ++nt) {
        int j = nt*16 + lr;
        sh8 bh[4], bl[4];
        #pragma unroll
        for (int ks = 0; ks < 4; ++ks) {
            int us = eidx(j, ks*32 + lk*8);
            bh[ks] = *(const sh8*)&Ehi[us];
            bl[ks] = *(const sh8*)&Elo[us];
        }
        #pragma unroll
        for (int mt = 0; mt < 2; ++mt)
            #pragma unroll
            for (int ks = 0; ks < 4; ++ks) {
                acc1[mt][nt] = MFMA_B16(A1[mt][ks], bh[ks], acc1[mt][nt]);
                acc1[mt][nt] = MFMA_B16(A1[mt][ks], bl[ks], acc1[mt][nt]);
            }
    }

    // ---- h = relu -> bf16 -> Ht ----
    #pragma unroll
    for (int mt = 0; mt < 2; ++mt)
        #pragma unroll
        for (int nt = 0; nt < 4; ++nt) {
            int o0 = w*32 + mt*16 + lk*4;
            int j  = nt*16 + lr;
            float h0 = fmaxf(acc1[mt][nt][0], 0.f);
            float h1 = fmaxf(acc1[mt][nt][1], 0.f);
            float h2 = fmaxf(acc1[mt][nt][2], 0.f);
            float h3 = fmaxf(acc1[mt][nt][3], 0.f);
            int us = eidx(j, o0);
            *(uint32_t*)&Ht[us]     = (uint32_t)f2bf(h0) | ((uint32_t)f2bf(h1) << 16);
            *(uint32_t*)&Ht[us + 2] = (uint32_t)f2bf(h2) | ((uint32_t)f2bf(h3) << 16);
        }
    __syncthreads();

    // ---- layer 2: acc = be2 + W2*h ----
    f32x4 acc2[2][4];
    #pragma unroll
    for (int mt = 0; mt < 2; ++mt) {
        float4 bv = *(const float4*)(be2 + w*32 + mt*16 + lk*4);
        #pragma unroll
        for (int nt = 0; nt < 4; ++nt) {
            acc2[mt][nt][0] = bv.x; acc2[mt][nt][1] = bv.y;
            acc2[mt][nt][2] = bv.z; acc2[mt][nt][3] = bv.w;
        }
    }
    #pragma unroll
    for (int nt = 0; nt < 4; ++nt) {
        int j = nt*16 + lr;
        sh8 hh[4];
        #pragma unroll
        for (int ks = 0; ks < 4; ++ks)
            hh[ks] = *(const sh8*)&Ht[eidx(j, ks*32 + lk*8)];
        #pragma unroll
        for (int mt = 0; mt < 2; ++mt)
            #pragma unroll
            for (int ks = 0; ks < 4; ++ks)
                acc2[mt][nt] = MFMA_B16(A2[mt][ks], hh[ks], acc2[mt][nt]);
    }

    // ---- epilogue: edges1 = (Ehi+Elo) + ae0*relu(acc2) ----
    #pragma unroll
    for (int mt = 0; mt < 2; ++mt) {
        int o0 = w*32 + mt*16 + lk*4;
        float4 a0v = *(const float4*)(ae0 + o0);
        float aev[4] = {a0v.x, a0v.y, a0v.z, a0v.w};
        #pragma unroll
        for (int nt = 0; nt < 4; ++nt) {
            int j = nt*16 + lr;
            int us = eidx(j, o0);
            sh4 eh = *(const sh4*)&Ehi[us];
            sh4 el = *(const sh4*)&Elo[us];
            #pragma unroll
            for (int r = 0; r < 4; ++r) {
                float e = bf2f((uint16_t)eh[r]) + bf2f((uint16_t)el[r]);
                float g = fmaxf(acc2[mt][nt][r], 0.f);
                e1out[(size_t)(b*CE_ + o0 + r)*SS_ + (size_t)i*S_ + j0 + j] = e + aev[r]*g;
            }
        }
    }
}

// ---------------- fused attention row kernel ----------------
__global__ __launch_bounds__(256)
void k_attn(const float* __restrict__ e1, float* __restrict__ ws,
            const float* __restrict__ Wk)
{
    __shared__ float qcol[AH_];
    __shared__ float qw[CE_ * 8];      // [c'][h]
    __shared__ float simL[H_ * S_];    // 8 x 256
    __shared__ float Etile[CE_ * 65];
    const int t = threadIdx.x;
    const int b = blockIdx.x >> 8, i = blockIdx.x & 255;
    const float* maskf = ws + OFF_MASK;

    qcol[t] = ws[OFF_Q + ((size_t)(b*AH_+t))*S_ + i];
    __syncthreads();
    #pragma unroll
    for (int k = 0; k < 4; ++k) {
        int idx = k*256 + t;
        int c = idx >> 3, h = idx & 7;
        float a = 0.f;
        #pragma unroll
        for (int aa = 0; aa < A_; ++aa)
            a = fmaf(qcol[h*A_ + aa], Wk[(h*A_+aa)*CNE_ + CN_ + c], a);
        qw[c*8 + h] = a;
    }
    __syncthreads();

    const float* Eb = e1 + ((size_t)(b*CE_)*S_ + i)*S_;
    float sv[8];
    #pragma unroll
    for (int h = 0; h < 8; ++h) sv[h] = 0.f;
    for (int c = 0; c < CE_; ++c) {
        float e = Eb[(size_t)c*SS_ + t];
        float4 q0 = *(const float4*)(qw + c*8);
        float4 q1 = *(const float4*)(qw + c*8 + 4);
        sv[0] = fmaf(q0.x, e, sv[0]); sv[1] = fmaf(q0.y, e, sv[1]);
        sv[2] = fmaf(q0.z, e, sv[2]); sv[3] = fmaf(q0.w, e, sv[3]);
        sv[4] = fmaf(q1.x, e, sv[4]); sv[5] = fmaf(q1.y, e, sv[5]);
        sv[6] = fmaf(q1.z, e, sv[6]); sv[7] = fmaf(q1.w, e, sv[7]);
    }
    const bool mj = maskf[b*S_ + t] != 0.f;
    #pragma unroll
    for (int h = 0; h < 8; ++h) simL[h*S_ + t] = mj ? sv[h] : -1e9f;
    __syncthreads();

    {
        const int h = t >> 5, l = t & 31;
        float vv[8]; float m = -3.4e38f;
        #pragma unroll
        for (int k = 0; k < 8; ++k) { vv[k] = simL[h*S_ + l + k*32]; m = fmaxf(m, vv[k]); }
        #pragma unroll
        for (int off = 16; off >= 1; off >>= 1) m = fmaxf(m, __shfl_xor(m, off, 32));
        float ssum = 0.f; float ex[8];
        #pragma unroll
        for (int k = 0; k < 8; ++k) { ex[k] = __expf(vv[k] - m); ssum += ex[k]; }
        #pragma unroll
        for (int off = 16; off >= 1; off >>= 1) ssum += __shfl_xor(ssum, off, 32);
        const float mi = maskf[b*S_ + i];
        const float rr = mi / ssum;
        #pragma unroll
        for (int k = 0; k < 8; ++k) simL[h*S_ + l + k*32] = ex[k] * rr;
    }
    __syncthreads();

    const int cp = t & 127, hg = t >> 7;
    float a4[4] = {0.f, 0.f, 0.f, 0.f};
    for (int jt = 0; jt < 4; ++jt) {
        #pragma unroll 4
        for (int r = 0; r < 32; ++r) {
            int idx = r*256 + t;
            int c = idx >> 6, j = idx & 63;
            Etile[c*65 + j] = Eb[(size_t)c*SS_ + jt*64 + j];
        }
        __syncthreads();
        for (int j = 0; j < 64; ++j) {
            float e = Etile[cp*65 + j];
            #pragma unroll
            for (int k = 0; k < 4; ++k)
                a4[k] = fmaf(e, simL[(hg*4+k)*S_ + jt*64 + j], a4[k]);
        }
        __syncthreads();
    }
    float* se = ws + OFF_SE + (size_t)(b*S_ + i)*1024;
    #pragma unroll
    for (int k = 0; k < 4; ++k) se[(hg*4+k)*128 + cp] = a4[k];
}

// ---------------- nf = vnode*mask_i + Wv_edge @ se ----------------
__global__ __launch_bounds__(256)
void k_nf(float* __restrict__ ws, const float* __restrict__ Wv)
{
    __shared__ float seL[1024];
    const int t = threadIdx.x;
    const int b = blockIdx.x >> 8, i = blockIdx.x & 255;
    const float* se = ws + OFF_SE + (size_t)(b*S_ + i)*1024;
    #pragma unroll
    for (int k = 0; k < 4; ++k) seL[k*256 + t] = se[k*256 + t];
    __syncthreads();
    const int h = t >> 5;
    float acc = 0.f;
    for (int c = 0; c < CE_; ++c)
        acc = fmaf(Wv[t*CNE_ + CN_ + c], seL[h*128 + c], acc);
    const float mi = ws[OFF_MASK + b*S_ + i];
    float nfv = ws[OFF_VN + ((size_t)(b*VH_+t))*S_ + i] * mi + acc;
    ws[OFF_NF + ((size_t)(b*VH_+t))*S_ + i] = nfv;
}

// ---------------- node output + Wnf ----------------
__global__ __launch_bounds__(256)
void k_node_out(float* __restrict__ ws, const float* __restrict__ Wo,
                const float* __restrict__ We, const float* __restrict__ an1,
                float* __restrict__ out_nodes)
{
    __shared__ float xs[VH_ * 8];
    const int t  = threadIdx.x;
    const int b  = blockIdx.x >> 5;
    const int s0 = (blockIdx.x & 31) * 8;
    #pragma unroll
    for (int r = 0; r < 8; ++r) {
        int idx = r*256 + t; int c = idx >> 3, s = idx & 7;
        xs[c*8+s] = ws[OFF_NF + ((size_t)(b*VH_+c))*S_ + s0 + s];
    }
    __syncthreads();
    float acc[8] = {0,0,0,0,0,0,0,0};
    for (int c = 0; c < VH_; ++c) {
        float w = Wo[t*VH_ + c];
        #pragma unroll
        for (int s = 0; s < 8; ++s) acc[s] = fmaf(w, xs[c*8+s], acc[s]);
    }
    float a1 = an1[t];
    #pragma unroll
    for (int s = 0; s < 8; ++s) {
        float mi = ws[OFF_MASK + b*S_ + s0 + s];
        out_nodes[((size_t)(b*CN_+t))*S_ + s0 + s] =
            (ws[OFF_N1 + ((size_t)(b*CN_+t))*S_ + s0 + s] + a1*acc[s]) * mi;
    }
    if (t < CE_) { // Wnf = We[:, :VH] @ nf
        float acc2[8] = {0,0,0,0,0,0,0,0};
        for (int c = 0; c < VH_; ++c) {
            float w = We[t*CNE_ + c];
            #pragma unroll
            for (int s = 0; s < 8; ++s) acc2[s] = fmaf(w, xs[c*8+s], acc2[s]);
        }
        #pragma unroll
        for (int s = 0; s < 8; ++s)
            ws[OFF_WNF + ((size_t)(b*CE_+t))*S_ + s0 + s] = acc2[s];
    }
}

// ---------------- edge output via split-bf16 MFMA (in-place on d_out edges) ----------------
// att = 0.5*(Wnf_i + Wnf_j) + We_edge @ edges1 ; out = (edges1 + ae1*att)*mi*mj
__global__ __launch_bounds__(256, 2)
void k_edge_out(float* __restrict__ e1, const float* __restrict__ ws,
                const float* __restrict__ ae1)
{
    __shared__ ushort Ehi[64 * 136];
    __shared__ ushort Elo[64 * 136];
    __shared__ float  wni_s[CE_];

    const int t  = threadIdx.x;
    const int b  = blockIdx.x >> 10;
    const int i  = (blockIdx.x >> 2) & 255;
    const int j0 = (blockIdx.x & 3) * 64;
    float* Eb = e1 + (size_t)b*CE_*SS_ + (size_t)i*S_ + j0;
    const float* Wnf   = ws + OFF_WNF;
    const float* maskf = ws + OFF_MASK;

    if (t < CE_) wni_s[t] = Wnf[(size_t)(b*CE_ + t)*S_ + i];

    // ---- stage hi/lo transposed ----
    {
        const int tj = t & 15;
        const int p0 = t >> 4;
        #pragma unroll
        for (int s = 0; s < 4; ++s) {
            int c = (s*16 + p0) * 2;
            float4 v0 = *(const float4*)(Eb + (size_t)c*SS_ + tj*4);
            float4 v1 = *(const float4*)(Eb + (size_t)(c+1)*SS_ + tj*4);
            float a0[4] = {v0.x, v0.y, v0.z, v0.w};
            float a1[4] = {v1.x, v1.y, v1.z, v1.w};
            #pragma unroll
            for (int jj = 0; jj < 4; ++jj) {
                int j = tj*4 + jj;
                uint16_t h0 = f2bf(a0[jj]); uint16_t l0 = f2bf(a0[jj] - bf2f(h0));
                uint16_t h1 = f2bf(a1[jj]); uint16_t l1 = f2bf(a1[jj] - bf2f(h1));
                int us = eidx(j, c);
                *(uint32_t*)&Ehi[us] = (uint32_t)h0 | ((uint32_t)h1 << 16);
                *(uint32_t*)&Elo[us] = (uint32_t)l0 | ((uint32_t)l1 << 16);
            }
        }
    }

    const int w  = t >> 6;
    const int l  = t & 63;
    const int lr = l & 15;
    const int lk = l >> 4;
    const ushort* wbe = (const ushort*)(ws + OFF_WBE);
    sh8 AE[2][4];
    #pragma unroll
    for (int mt = 0; mt < 2; ++mt) {
        int o = w*32 + mt*16 + lr;
        #pragma unroll
        for (int ks = 0; ks < 4; ++ks)
            AE[mt][ks] = *(const sh8*)(wbe + o*CE_ + ks*32 + lk*8);
    }

    f32x4 acc[2][4];
    #pragma unroll
    for (int mt = 0; mt < 2; ++mt)
        #pragma unroll
        for (int nt = 0; nt < 4; ++nt)
            acc[mt][nt] = (f32x4){0.f, 0.f, 0.f, 0.f};
    __syncthreads();
    #pragma unroll
    for (int nt = 0; nt < 4; ++nt) {
        int j = nt*16 + lr;
        sh8 bh[4], bl[4];
        #pragma unroll
        for (int ks = 0; ks < 4; ++ks) {
            int us = eidx(j, ks*32 + lk*8);
            bh[ks] = *(const sh8*)&Ehi[us];
            bl[ks] = *(const sh8*)&Elo[us];
        }
        #pragma unroll
        for (int mt = 0; mt < 2; ++mt)
            #pragma unroll
            for (int ks = 0; ks < 4; ++ks) {
                acc[mt][nt] = MFMA_B16(AE[mt][ks], bh[ks], acc[mt][nt]);
                acc[mt][nt] = MFMA_B16(AE[mt][ks], bl[ks], acc[mt][nt]);
            }
    }

    // ---- epilogue ----
    const float mi = maskf[b*S_ + i];
    #pragma unroll
    for (int mt = 0; mt < 2; ++mt) {
        int o0 = w*32 + mt*16 + lk*4;
        float4 a1v = *(const float4*)(ae1 + o0);
        float aev[4] = {a1v.x, a1v.y, a1v.z, a1v.w};
        #pragma unroll
        for (int nt = 0; nt < 4; ++nt) {
            int j  = nt*16 + lr;
            int jg = j0 + j;
            float mj = maskf[b*S_ + jg];
            int us = eidx(j, o0);
            sh4 eh = *(const sh4*)&Ehi[us];
            sh4 el = *(const sh4*)&Elo[us];
            #pragma unroll
            for (int r = 0; r < 4; ++r) {
                float e   = bf2f((uint16_t)eh[r]) + bf2f((uint16_t)el[r]);
                float att = 0.5f*(wni_s[o0+r] + Wnf[(size_t)(b*CE_+o0+r)*S_ + jg])
                          + acc[mt][nt][r];
                Eb[(size_t)(o0+r)*SS_ + j] = (e + aev[r]*att) * (mi * mj);
            }
        }
    }
}

// ---------------- launch ----------------
extern "C" void kernel_launch(void* const* d_in, const int* in_sizes, int n_in,
                              void* d_out, int out_size, void* d_ws, size_t ws_size,
                              hipStream_t stream)
{
    const float* nodes = (const float*)d_in[0];
    const float* edges = (const float*)d_in[1];
    const unsigned char* mraw = (const unsigned char*)d_in[2];
    const float* Wq  = (const float*)d_in[3];
    const float* Wk  = (const float*)d_in[4];
    const float* Wv  = (const float*)d_in[5];
    const float* Wo  = (const float*)d_in[6];
    const float* We  = (const float*)d_in[7];
    const float* Wm1 = (const float*)d_in[8];
    const float* bm1 = (const float*)d_in[9];
    const float* Wm2 = (const float*)d_in[10];
    const float* bm2 = (const float*)d_in[11];
    const float* We1 = (const float*)d_in[12];
    const float* be1 = (const float*)d_in[13];
    const float* We2 = (const float*)d_in[14];
    const float* be2 = (const float*)d_in[15];
    const float* an0 = (const float*)d_in[16];
    const float* an1 = (const float*)d_in[17];
    const float* ae0 = (const float*)d_in[18];
    const float* ae1 = (const float*)d_in[19];

    float* ws = (float*)d_ws;
    float* out_nodes = (float*)d_out;
    float* out_edges = out_nodes + (size_t)B_*CN_*S_; // edges1 lives here, updated in-place

    k_mask_norm  <<<1,    512, 0, stream>>>(mraw, ws);
    k_wprep      <<<192,  256, 0, stream>>>(We1, We2, We, ws);
    k_node_mlp_qv<<<64,   256, 0, stream>>>(nodes, Wm1, bm1, Wm2, bm2, an0, Wq, Wv, ws);
    k_edge_mlp   <<<2048, 256, 0, stream>>>(edges, ws, be1, be2, ae0, out_edges);
    k_attn       <<<512,  256, 0, stream>>>(out_edges, ws, Wk);
    k_nf         <<<512,  256, 0, stream>>>(ws, Wv);
    k_node_out   <<<64,   256, 0, stream>>>(ws, Wo, We, an1, out_nodes);
    k_edge_out   <<<2048, 256, 0, stream>>>(out_edges, ws, ae1);
}

// Round 6
// 312.682 us; speedup vs baseline: 1.5551x; 1.0542x over previous
//
#include <hip/hip_runtime.h>
#include <hip/hip_bf16.h>
#include <cstdint>
#include <cstddef>

// ---------------- problem constants ----------------
constexpr int B_  = 2;
constexpr int S_  = 256;
constexpr int CN_ = 256;
constexpr int CE_ = 128;
constexpr int A_  = 32;
constexpr int H_  = 8;
constexpr int V_  = 32;
constexpr int AH_ = A_ * H_;    // 256
constexpr int VH_ = V_ * H_;    // 256
constexpr int SS_ = S_ * S_;    // 65536
constexpr int CNE_ = CN_ + CE_; // 384

// ---------------- workspace layout (float offsets) ----------------
constexpr size_t OFF_N1   = 0;                                  // nodes1 (B,CN,S)
constexpr size_t OFF_Q    = OFF_N1  + (size_t)B_*CN_*S_;        // q * 1/sqrt(A) (B,AH,S)
constexpr size_t OFF_VN   = OFF_Q   + (size_t)B_*AH_*S_;        // vnode (B,VH,S)
constexpr size_t OFF_NF   = OFF_VN  + (size_t)B_*VH_*S_;        // nf (B,VH,S)
constexpr size_t OFF_WNF  = OFF_NF  + (size_t)B_*VH_*S_;        // Wnf (B,CE,S)
constexpr size_t OFF_SE   = OFF_WNF + (size_t)B_*CE_*S_;        // se (B*S, H*CE=1024)
constexpr size_t OFF_QW   = OFF_SE  + (size_t)B_*S_*1024;       // qw (B*S, 128c x 8h)
constexpr size_t OFF_WB1  = OFF_QW  + (size_t)B_*S_*1024;       // We1 bf16 [o][c] (as ushort)
constexpr size_t OFF_WB2  = OFF_WB1 + 16384;                    // We2 bf16 [o][c]
constexpr size_t OFF_WBE  = OFF_WB2 + 16384;                    // We[:,256:384] bf16 [o][c]
constexpr size_t OFF_MASK = OFF_WBE + 16384;                    // canonical f32 mask (B*S)

// ---------------- bf16 helpers ----------------
__device__ inline uint16_t f2bf(float x) {
    uint32_t u = __float_as_uint(x);
    uint32_t r = (u + 0x7fffu + ((u >> 16) & 1u)) >> 16;  // RNE
    return (uint16_t)r;
}
__device__ inline float bf2f(uint16_t h) {
    return __uint_as_float(((uint32_t)h) << 16);
}
// packed split: word = hi16<<16 | lo16 ; value ≈ bf2f(hi)+bf2f(lo) (±2^-16 rel)
__device__ inline uint32_t pack_split(float v) {
    uint32_t u  = __float_as_uint(v);
    uint32_t hm = u & 0xffff0000u;
    return hm | (__float_as_uint(v - __uint_as_float(hm)) >> 16);
}
__device__ inline float unpack_f32(uint32_t p) {
    return __uint_as_float(p & 0xffff0000u) + __uint_as_float(p << 16);
}

typedef __attribute__((ext_vector_type(8))) short sh8;
typedef __attribute__((ext_vector_type(4))) short sh4;
typedef __attribute__((ext_vector_type(4))) float f32x4;

#define MFMA_B16(a, b, c) __builtin_amdgcn_mfma_f32_16x16x32_bf16((a), (b), (c), 0, 0, 0)

// LDS tile geometry: [j][c] bf16, row stride 136 ushorts + XOR-swizzle bits 3..5.
__device__ inline int eidx(int j, int c) {
    return (j * 136 + c) ^ (((j >> 3) & 7) << 3);
}

// 4-column GEMM micro: acc[0..3] += W[t][c] * xs[c][0..3], K=256, float4 loads.
#define GEMM4_K256(WROW, XS, A0, A1, A2, A3)                                   \
    for (int c = 0; c < 256; c += 4) {                                         \
        float4 w  = *(const float4*)((WROW) + c);                              \
        float4 x0 = *(const float4*)((XS) + (c+0)*4);                          \
        float4 x1 = *(const float4*)((XS) + (c+1)*4);                          \
        float4 x2 = *(const float4*)((XS) + (c+2)*4);                          \
        float4 x3 = *(const float4*)((XS) + (c+3)*4);                          \
        A0 = fmaf(w.x,x0.x,fmaf(w.y,x1.x,fmaf(w.z,x2.x,fmaf(w.w,x3.x,A0))));   \
        A1 = fmaf(w.x,x0.y,fmaf(w.y,x1.y,fmaf(w.z,x2.y,fmaf(w.w,x3.y,A1))));   \
        A2 = fmaf(w.x,x0.z,fmaf(w.y,x1.z,fmaf(w.z,x2.z,fmaf(w.w,x3.z,A2))));   \
        A3 = fmaf(w.x,x0.w,fmaf(w.y,x1.w,fmaf(w.z,x2.w,fmaf(w.w,x3.w,A3))));   \
    }

// ---------------- mask normalization ----------------
__global__ void k_mask_norm(const unsigned char* __restrict__ mraw,
                            float* __restrict__ ws)
{
    int t = threadIdx.x; // one block of 512 threads covers B*S
    unsigned char b1 = mraw[1], b2 = mraw[2];
    float mv;
    if (b1 == (unsigned char)1) {
        mv = mraw[t] ? 1.f : 0.f;                       // bool bytes
    } else if (b2 == (unsigned char)128) {
        mv = (((const float*)mraw)[t] != 0.f) ? 1.f : 0.f; // float32
    } else {
        mv = (((const int*)mraw)[t] != 0) ? 1.f : 0.f;  // int32
    }
    ws[OFF_MASK + t] = mv;
}

// ---------------- weight prep: f32 -> bf16 ----------------
__global__ void k_wprep(const float* __restrict__ We1_,
                        const float* __restrict__ We2_,
                        const float* __restrict__ We_,
                        float* __restrict__ ws)
{
    int idx = blockIdx.x * 256 + threadIdx.x;   // 0..49151
    int m = idx >> 14;
    int r = idx & 16383;
    int o = r >> 7, c = r & 127;
    ushort* wb1 = (ushort*)(ws + OFF_WB1);
    ushort* wb2 = (ushort*)(ws + OFF_WB2);
    ushort* wbe = (ushort*)(ws + OFF_WBE);
    if (m == 0)      wb1[r] = f2bf(We1_[o*CE_ + c]);
    else if (m == 1) wb2[r] = f2bf(We2_[o*CE_ + c]);
    else             wbe[r] = f2bf(We_[o*CNE_ + CN_ + c]);
}

// ---------------- node MLP + q + vnode (fused), 4 cols/block ----------------
__global__ __launch_bounds__(256)
void k_node_mlp_qv(const float* __restrict__ nodes,
                   const float* __restrict__ Wm1, const float* __restrict__ bm1,
                   const float* __restrict__ Wm2, const float* __restrict__ bm2,
                   const float* __restrict__ an0,
                   const float* __restrict__ Wq,  const float* __restrict__ Wv,
                   float* __restrict__ ws)
{
    __shared__ float xs[CN_ * 4];
    __shared__ float hs[CN_ * 4];
    const int t  = threadIdx.x;
    const int b  = blockIdx.x >> 6;           // 64 blocks per batch
    const int s0 = (blockIdx.x & 63) * 4;

    { // stage: thread t = channel t, 4 consecutive columns
        float4 nv = *(const float4*)(nodes + (size_t)(b*CN_+t)*S_ + s0);
        xs[t*4+0]=nv.x; xs[t*4+1]=nv.y; xs[t*4+2]=nv.z; xs[t*4+3]=nv.w;
    }
    __syncthreads();

    float a0, a1, a2, a3;
    { // layer 1
        float bv = bm1[t]; a0=bv; a1=bv; a2=bv; a3=bv;
        GEMM4_K256(Wm1 + t*CN_, xs, a0, a1, a2, a3);
        hs[t*4+0]=fmaxf(a0,0.f); hs[t*4+1]=fmaxf(a1,0.f);
        hs[t*4+2]=fmaxf(a2,0.f); hs[t*4+3]=fmaxf(a3,0.f);
    }
    __syncthreads();
    { // layer 2
        float bv = bm2[t]; a0=bv; a1=bv; a2=bv; a3=bv;
        GEMM4_K256(Wm2 + t*CN_, hs, a0, a1, a2, a3);
    }
    { // ReZero residual -> nodes1 (overwrite own xs row)
        float an = an0[t];
        float n0 = xs[t*4+0] + an*fmaxf(a0,0.f);
        float n1 = xs[t*4+1] + an*fmaxf(a1,0.f);
        float n2 = xs[t*4+2] + an*fmaxf(a2,0.f);
        float n3 = xs[t*4+3] + an*fmaxf(a3,0.f);
        xs[t*4+0]=n0; xs[t*4+1]=n1; xs[t*4+2]=n2; xs[t*4+3]=n3;
        *(float4*)(ws + OFF_N1 + (size_t)(b*CN_+t)*S_ + s0) = make_float4(n0,n1,n2,n3);
    }
    __syncthreads();

    { // q (1/sqrt(A) folded)
        a0=0.f; a1=0.f; a2=0.f; a3=0.f;
        GEMM4_K256(Wq + t*CN_, xs, a0, a1, a2, a3);
        const float rsA = 0.1767766952966369f;
        *(float4*)(ws + OFF_Q + (size_t)(b*AH_+t)*S_ + s0) =
            make_float4(a0*rsA, a1*rsA, a2*rsA, a3*rsA);
    }
    { // vnode = Wv[:, :CN] @ nodes1
        a0=0.f; a1=0.f; a2=0.f; a3=0.f;
        GEMM4_K256(Wv + t*CNE_, xs, a0, a1, a2, a3);
        *(float4*)(ws + OFF_VN + (size_t)(b*VH_+t)*S_ + s0) = make_float4(a0,a1,a2,a3);
    }
}

// ---------------- qw precompute: qw[b,i][c,8h] = sum_a q[b,h,a,i]*Wk_edge ----------------
__global__ __launch_bounds__(256)
void k_qw(float* __restrict__ ws, const float* __restrict__ Wk)
{
    __shared__ float qcol[AH_];
    const int t = threadIdx.x;
    const int b = blockIdx.x >> 8, i = blockIdx.x & 255;
    qcol[t] = ws[OFF_Q + (size_t)(b*AH_+t)*S_ + i];
    __syncthreads();
    const int c  = t & 127;
    const int h0 = (t >> 7) * 4;
    float acc[4] = {0.f, 0.f, 0.f, 0.f};
    for (int aa = 0; aa < A_; ++aa) {
        #pragma unroll
        for (int k = 0; k < 4; ++k) {
            int ha = (h0 + k)*A_ + aa;
            acc[k] = fmaf(qcol[ha], Wk[(size_t)ha*CNE_ + CN_ + c], acc[k]);
        }
    }
    float* q = ws + OFF_QW + (size_t)(b*S_ + i)*1024;
    #pragma unroll
    for (int k = 0; k < 4; ++k) q[c*8 + h0 + k] = acc[k];
}

// ---------------- edge MLP via split-bf16 MFMA; OUTPUT = packed hi|lo u32 ----------------
__global__ __launch_bounds__(256, 2)
void k_edge_mlp(const float* __restrict__ edges,
                const float* __restrict__ ws,
                const float* __restrict__ be1, const float* __restrict__ be2,
                const float* __restrict__ ae0,
                uint32_t* __restrict__ e1out)
{
    __shared__ ushort Ehi[64 * 136];
    __shared__ ushort Elo[64 * 136];
    __shared__ ushort Ht [64 * 136];

    const int t  = threadIdx.x;
    const int b  = blockIdx.x >> 10;
    const int i  = (blockIdx.x >> 2) & 255;
    const int j0 = (blockIdx.x & 3) * 64;
    const float* Eb = edges + (size_t)b*CE_*SS_ + (size_t)i*S_ + j0;

    // ---- stage: load f32, truncation-split hi/lo, write transposed ----
    {
        const int tj = t & 15;       // j-quad
        const int p0 = t >> 4;       // c-pair
        #pragma unroll
        for (int s = 0; s < 4; ++s) {
            int c = (s*16 + p0) * 2;
            float4 v0 = *(const float4*)(Eb + (size_t)c*SS_ + tj*4);
            float4 v1 = *(const float4*)(Eb + (size_t)(c+1)*SS_ + tj*4);
            float q0[4] = {v0.x, v0.y, v0.z, v0.w};
            float q1[4] = {v1.x, v1.y, v1.z, v1.w};
            #pragma unroll
            for (int jj = 0; jj < 4; ++jj) {
                int j = tj*4 + jj;
                uint32_t u0 = __float_as_uint(q0[jj]), u1 = __float_as_uint(q1[jj]);
                uint32_t h0m = u0 & 0xffff0000u, h1m = u1 & 0xffff0000u;
                uint32_t hiw = (u0 >> 16) | h1m;
                uint32_t low = (__float_as_uint(q0[jj] - __uint_as_float(h0m)) >> 16)
                             | (__float_as_uint(q1[jj] - __uint_as_float(h1m)) & 0xffff0000u);
                int us = eidx(j, c);
                *(uint32_t*)&Ehi[us] = hiw;
                *(uint32_t*)&Elo[us] = low;
            }
        }
    }

    // ---- preload A fragments ----
    const int w  = t >> 6;
    const int l  = t & 63;
    const int lr = l & 15;
    const int lk = l >> 4;
    const ushort* wb1 = (const ushort*)(ws + OFF_WB1);
    const ushort* wb2 = (const ushort*)(ws + OFF_WB2);
    sh8 A1[2][4], A2[2][4];
    #pragma unroll
    for (int mt = 0; mt < 2; ++mt) {
        int o = w*32 + mt*16 + lr;
        #pragma unroll
        for (int ks = 0; ks < 4; ++ks) {
            A1[mt][ks] = *(const sh8*)(wb1 + o*CE_ + ks*32 + lk*8);
            A2[mt][ks] = *(const sh8*)(wb2 + o*CE_ + ks*32 + lk*8);
        }
    }

    // ---- layer 1 ----
    f32x4 acc1[2][4];
    #pragma unroll
    for (int mt = 0; mt < 2; ++mt) {
        float4 bv = *(const float4*)(be1 + w*32 + mt*16 + lk*4);
        #pragma unroll
        for (int nt = 0; nt < 4; ++nt) {
            acc1[mt][nt][0] = bv.x; acc1[mt][nt][1] = bv.y;
            acc1[mt][nt][2] = bv.z; acc1[mt][nt][3] = bv.w;
        }
    }
    __syncthreads();
    #pragma unroll
    for (int nt = 0; nt < 4; ++nt) {
        int j = nt*16 + lr;
        sh8 bh[4], bl[4];
        #pragma unroll
        for (int ks = 0; ks < 4; ++ks) {
            int us = eidx(j, ks*32 + lk*8);
            bh[ks] = *(const sh8*)&Ehi[us];
            bl[ks] = *(const sh8*)&Elo[us];
        }
        #pragma unroll
        for (int mt = 0; mt < 2; ++mt)
            #pragma unroll
            for (int ks = 0; ks < 4; ++ks) {
                acc1[mt][nt] = MFMA_B16(A1[mt][ks], bh[ks], acc1[mt][nt]);
                acc1[mt][nt] = MFMA_B16(A1[mt][ks], bl[ks], acc1[mt][nt]);
            }
    }

    // ---- h = relu -> bf16 (trunc) -> Ht ----
    #pragma unroll
    for (int mt = 0; mt < 2; ++mt)
        #pragma unroll
        for (int nt = 0; nt < 4; ++nt) {
            int o0 = w*32 + mt*16 + lk*4;
            int j  = nt*16 + lr;
            uint32_t u0 = __float_as_uint(fmaxf(acc1[mt][nt][0], 0.f));
            uint32_t u1 = __float_as_uint(fmaxf(acc1[mt][nt][1], 0.f));
            uint32_t u2 = __float_as_uint(fmaxf(acc1[mt][nt][2], 0.f));
            uint32_t u3 = __float_as_uint(fmaxf(acc1[mt][nt][3], 0.f));
            int us = eidx(j, o0);
            *(uint32_t*)&Ht[us]     = (u0 >> 16) | (u1 & 0xffff0000u);
            *(uint32_t*)&Ht[us + 2] = (u2 >> 16) | (u3 & 0xffff0000u);
        }
    __syncthreads();

    // ---- layer 2 ----
    f32x4 acc2[2][4];
    #pragma unroll
    for (int mt = 0; mt < 2; ++mt) {
        float4 bv = *(const float4*)(be2 + w*32 + mt*16 + lk*4);
        #pragma unroll
        for (int nt = 0; nt < 4; ++nt) {
            acc2[mt][nt][0] = bv.x; acc2[mt][nt][1] = bv.y;
            acc2[mt][nt][2] = bv.z; acc2[mt][nt][3] = bv.w;
        }
    }
    #pragma unroll
    for (int nt = 0; nt < 4; ++nt) {
        int j = nt*16 + lr;
        sh8 hh[4];
        #pragma unroll
        for (int ks = 0; ks < 4; ++ks)
            hh[ks] = *(const sh8*)&Ht[eidx(j, ks*32 + lk*8)];
        #pragma unroll
        for (int mt = 0; mt < 2; ++mt)
            #pragma unroll
            for (int ks = 0; ks < 4; ++ks)
                acc2[mt][nt] = MFMA_B16(A2[mt][ks], hh[ks], acc2[mt][nt]);
    }

    // ---- epilogue: edges1 = (Ehi+Elo) + ae0*relu(acc2), store PACKED ----
    #pragma unroll
    for (int mt = 0; mt < 2; ++mt) {
        int o0 = w*32 + mt*16 + lk*4;
        float4 a0v = *(const float4*)(ae0 + o0);
        float aev[4] = {a0v.x, a0v.y, a0v.z, a0v.w};
        #pragma unroll
        for (int nt = 0; nt < 4; ++nt) {
            int j = nt*16 + lr;
            int us = eidx(j, o0);
            sh4 eh = *(const sh4*)&Ehi[us];
            sh4 el = *(const sh4*)&Elo[us];
            #pragma unroll
            for (int r = 0; r < 4; ++r) {
                float e = bf2f((uint16_t)eh[r]) + bf2f((uint16_t)el[r]);
                float g = fmaxf(acc2[mt][nt][r], 0.f);
                e1out[(size_t)(b*CE_ + o0 + r)*SS_ + (size_t)i*S_ + j0 + j] =
                    pack_split(e + aev[r]*g);
            }
        }
    }
}

// ---------------- fused attention row kernel (packed e1 input) ----------------
__global__ __launch_bounds__(256)
void k_attn(const uint32_t* __restrict__ e1, float* __restrict__ ws)
{
    __shared__ float qw[CE_ * 8];      // [c'][h]
    __shared__ float simL[H_ * S_];    // 8 x 256
    __shared__ float Etile[CE_ * 65];
    const int t = threadIdx.x;
    const int b = blockIdx.x >> 8, i = blockIdx.x & 255;
    const float* maskf = ws + OFF_MASK;

    { // stage precomputed qw row (coalesced float4)
        const float4* qwg = (const float4*)(ws + OFF_QW + (size_t)(b*S_ + i)*1024);
        ((float4*)qw)[t] = qwg[t];
    }
    __syncthreads();

    const uint32_t* Eb = e1 + ((size_t)(b*CE_)*S_ + i)*S_;
    float sv[8];
    #pragma unroll
    for (int h = 0; h < 8; ++h) sv[h] = 0.f;
    for (int c = 0; c < CE_; ++c) {
        float e = unpack_f32(Eb[(size_t)c*SS_ + t]);
        float4 q0 = *(const float4*)(qw + c*8);
        float4 q1 = *(const float4*)(qw + c*8 + 4);
        sv[0] = fmaf(q0.x, e, sv[0]); sv[1] = fmaf(q0.y, e, sv[1]);
        sv[2] = fmaf(q0.z, e, sv[2]); sv[3] = fmaf(q0.w, e, sv[3]);
        sv[4] = fmaf(q1.x, e, sv[4]); sv[5] = fmaf(q1.y, e, sv[5]);
        sv[6] = fmaf(q1.z, e, sv[6]); sv[7] = fmaf(q1.w, e, sv[7]);
    }
    const bool mj = maskf[b*S_ + t] != 0.f;
    #pragma unroll
    for (int h = 0; h < 8; ++h) simL[h*S_ + t] = mj ? sv[h] : -1e9f;
    __syncthreads();

    { // masked softmax per head
        const int h = t >> 5, l = t & 31;
        float vv[8]; float m = -3.4e38f;
        #pragma unroll
        for (int k = 0; k < 8; ++k) { vv[k] = simL[h*S_ + l + k*32]; m = fmaxf(m, vv[k]); }
        #pragma unroll
        for (int off = 16; off >= 1; off >>= 1) m = fmaxf(m, __shfl_xor(m, off, 32));
        float ssum = 0.f; float ex[8];
        #pragma unroll
        for (int k = 0; k < 8; ++k) { ex[k] = __expf(vv[k] - m); ssum += ex[k]; }
        #pragma unroll
        for (int off = 16; off >= 1; off >>= 1) ssum += __shfl_xor(ssum, off, 32);
        const float mi = maskf[b*S_ + i];
        const float rr = mi / ssum;
        #pragma unroll
        for (int k = 0; k < 8; ++k) simL[h*S_ + l + k*32] = ex[k] * rr;
    }
    __syncthreads();

    // se[h][c'] = sum_j sim[h][j] * E1[c'][i][j]
    const int cp = t & 127, hg = t >> 7;
    float a4[4] = {0.f, 0.f, 0.f, 0.f};
    for (int jt = 0; jt < 4; ++jt) {
        #pragma unroll 4
        for (int r = 0; r < 32; ++r) {
            int idx = r*256 + t;
            int c = idx >> 6, j = idx & 63;
            Etile[c*65 + j] = unpack_f32(Eb[(size_t)c*SS_ + jt*64 + j]);
        }
        __syncthreads();
        for (int j = 0; j < 64; ++j) {
            float e = Etile[cp*65 + j];
            #pragma unroll
            for (int k = 0; k < 4; ++k)
                a4[k] = fmaf(e, simL[(hg*4+k)*S_ + jt*64 + j], a4[k]);
        }
        __syncthreads();
    }
    float* se = ws + OFF_SE + (size_t)(b*S_ + i)*1024;
    #pragma unroll
    for (int k = 0; k < 4; ++k) se[(hg*4+k)*128 + cp] = a4[k];
}

// ---------------- nf = vnode*mask_i + Wv_edge @ se ----------------
__global__ __launch_bounds__(256)
void k_nf(float* __restrict__ ws, const float* __restrict__ Wv)
{
    __shared__ float seL[1024];
    const int t = threadIdx.x;
    const int b = blockIdx.x >> 8, i = blockIdx.x & 255;
    const float* se = ws + OFF_SE + (size_t)(b*S_ + i)*1024;
    #pragma unroll
    for (int k = 0; k < 4; ++k) seL[k*256 + t] = se[k*256 + t];
    __syncthreads();
    const int h = t >> 5;
    float acc = 0.f;
    for (int c = 0; c < CE_; ++c)
        acc = fmaf(Wv[t*CNE_ + CN_ + c], seL[h*128 + c], acc);
    const float mi = ws[OFF_MASK + b*S_ + i];
    float nfv = ws[OFF_VN + ((size_t)(b*VH_+t))*S_ + i] * mi + acc;
    ws[OFF_NF + ((size_t)(b*VH_+t))*S_ + i] = nfv;
}

// ---------------- node output + Wnf, 4 cols/block ----------------
__global__ __launch_bounds__(256)
void k_node_out(float* __restrict__ ws, const float* __restrict__ Wo,
                const float* __restrict__ We, const float* __restrict__ an1,
                float* __restrict__ out_nodes)
{
    __shared__ float xs[VH_ * 4];
    const int t  = threadIdx.x;
    const int b  = blockIdx.x >> 6;
    const int s0 = (blockIdx.x & 63) * 4;
    {
        float4 nv = *(const float4*)(ws + OFF_NF + (size_t)(b*VH_+t)*S_ + s0);
        xs[t*4+0]=nv.x; xs[t*4+1]=nv.y; xs[t*4+2]=nv.z; xs[t*4+3]=nv.w;
    }
    __syncthreads();
    float a0=0.f, a1=0.f, a2=0.f, a3=0.f;
    GEMM4_K256(Wo + t*VH_, xs, a0, a1, a2, a3);
    {
        float aw = an1[t];
        float4 n1 = *(const float4*)(ws + OFF_N1 + (size_t)(b*CN_+t)*S_ + s0);
        float4 mk = *(const float4*)(ws + OFF_MASK + b*S_ + s0);
        *(float4*)(out_nodes + (size_t)(b*CN_+t)*S_ + s0) = make_float4(
            (n1.x + aw*a0) * mk.x, (n1.y + aw*a1) * mk.y,
            (n1.z + aw*a2) * mk.z, (n1.w + aw*a3) * mk.w);
    }
    if (t < CE_) { // Wnf = We[:, :VH] @ nf
        a0=0.f; a1=0.f; a2=0.f; a3=0.f;
        GEMM4_K256(We + t*CNE_, xs, a0, a1, a2, a3);
        *(float4*)(ws + OFF_WNF + (size_t)(b*CE_+t)*S_ + s0) = make_float4(a0,a1,a2,a3);
    }
}

// ---------------- edge output (packed in, f32 out, in-place on d_out edges) ----------------
__global__ __launch_bounds__(256, 2)
void k_edge_out(const uint32_t* __restrict__ e1p, float* __restrict__ e1f,
                const float* __restrict__ ws, const float* __restrict__ ae1)
{
    __shared__ ushort Ehi[64 * 136];
    __shared__ ushort Elo[64 * 136];
    __shared__ float  wni_s[CE_];

    const int t  = threadIdx.x;
    const int b  = blockIdx.x >> 10;
    const int i  = (blockIdx.x >> 2) & 255;
    const int j0 = (blockIdx.x & 3) * 64;
    const uint32_t* Ebp = e1p + (size_t)b*CE_*SS_ + (size_t)i*S_ + j0;
    float*          Ebf = e1f + (size_t)b*CE_*SS_ + (size_t)i*S_ + j0;
    const float* Wnf   = ws + OFF_WNF;
    const float* maskf = ws + OFF_MASK;

    if (t < CE_) wni_s[t] = Wnf[(size_t)(b*CE_ + t)*S_ + i];

    // ---- stage: unpack packed words directly into hi/lo LDS ----
    {
        const int tj = t & 15;
        const int p0 = t >> 4;
        #pragma unroll
        for (int s = 0; s < 4; ++s) {
            int c = (s*16 + p0) * 2;
            uint4 v0 = *(const uint4*)(Ebp + (size_t)c*SS_ + tj*4);
            uint4 v1 = *(const uint4*)(Ebp + (size_t)(c+1)*SS_ + tj*4);
            uint32_t w0[4] = {v0.x, v0.y, v0.z, v0.w};
            uint32_t w1[4] = {v1.x, v1.y, v1.z, v1.w};
            #pragma unroll
            for (int jj = 0; jj < 4; ++jj) {
                int j = tj*4 + jj;
                int us = eidx(j, c);
                *(uint32_t*)&Ehi[us] = (w0[jj] >> 16) | (w1[jj] & 0xffff0000u);
                *(uint32_t*)&Elo[us] = (w0[jj] & 0xffffu) | (w1[jj] << 16);
            }
        }
    }

    const int w  = t >> 6;
    const int l  = t & 63;
    const int lr = l & 15;
    const int lk = l >> 4;
    const ushort* wbe = (const ushort*)(ws + OFF_WBE);
    sh8 AE[2][4];
    #pragma unroll
    for (int mt = 0; mt < 2; ++mt) {
        int o = w*32 + mt*16 + lr;
        #pragma unroll
        for (int ks = 0; ks < 4; ++ks)
            AE[mt][ks] = *(const sh8*)(wbe + o*CE_ + ks*32 + lk*8);
    }

    f32x4 acc[2][4];
    #pragma unroll
    for (int mt = 0; mt < 2; ++mt)
        #pragma unroll
        for (int nt = 0; nt < 4; ++nt)
            acc[mt][nt] = (f32x4){0.f, 0.f, 0.f, 0.f};
    __syncthreads();
    #pragma unroll
    for (int nt = 0; nt < 4; ++nt) {
        int j = nt*16 + lr;
        sh8 bh[4], bl[4];
        #pragma unroll
        for (int ks = 0; ks < 4; ++ks) {
            int us = eidx(j, ks*32 + lk*8);
            bh[ks] = *(const sh8*)&Ehi[us];
            bl[ks] = *(const sh8*)&Elo[us];
        }
        #pragma unroll
        for (int mt = 0; mt < 2; ++mt)
            #pragma unroll
            for (int ks = 0; ks < 4; ++ks) {
                acc[mt][nt] = MFMA_B16(AE[mt][ks], bh[ks], acc[mt][nt]);
                acc[mt][nt] = MFMA_B16(AE[mt][ks], bl[ks], acc[mt][nt]);
            }
    }

    // ---- epilogue ----
    const float mi = maskf[b*S_ + i];
    #pragma unroll
    for (int mt = 0; mt < 2; ++mt) {
        int o0 = w*32 + mt*16 + lk*4;
        float4 a1v = *(const float4*)(ae1 + o0);
        float aev[4] = {a1v.x, a1v.y, a1v.z, a1v.w};
        #pragma unroll
        for (int nt = 0; nt < 4; ++nt) {
            int j  = nt*16 + lr;
            int jg = j0 + j;
            float mj = maskf[b*S_ + jg];
            int us = eidx(j, o0);
            sh4 eh = *(const sh4*)&Ehi[us];
            sh4 el = *(const sh4*)&Elo[us];
            #pragma unroll
            for (int r = 0; r < 4; ++r) {
                float e   = bf2f((uint16_t)eh[r]) + bf2f((uint16_t)el[r]);
                float att = 0.5f*(wni_s[o0+r] + Wnf[(size_t)(b*CE_+o0+r)*S_ + jg])
                          + acc[mt][nt][r];
                Ebf[(size_t)(o0+r)*SS_ + j] = (e + aev[r]*att) * (mi * mj);
            }
        }
    }
}

// ---------------- launch ----------------
extern "C" void kernel_launch(void* const* d_in, const int* in_sizes, int n_in,
                              void* d_out, int out_size, void* d_ws, size_t ws_size,
                              hipStream_t stream)
{
    const float* nodes = (const float*)d_in[0];
    const float* edges = (const float*)d_in[1];
    const unsigned char* mraw = (const unsigned char*)d_in[2];
    const float* Wq  = (const float*)d_in[3];
    const float* Wk  = (const float*)d_in[4];
    const float* Wv  = (const float*)d_in[5];
    const float* Wo  = (const float*)d_in[6];
    const float* We  = (const float*)d_in[7];
    const float* Wm1 = (const float*)d_in[8];
    const float* bm1 = (const float*)d_in[9];
    const float* Wm2 = (const float*)d_in[10];
    const float* bm2 = (const float*)d_in[11];
    const float* We1 = (const float*)d_in[12];
    const float* be1 = (const float*)d_in[13];
    const float* We2 = (const float*)d_in[14];
    const float* be2 = (const float*)d_in[15];
    const float* an0 = (const float*)d_in[16];
    const float* an1 = (const float*)d_in[17];
    const float* ae0 = (const float*)d_in[18];
    const float* ae1 = (const float*)d_in[19];

    float* ws = (float*)d_ws;
    float* out_nodes = (float*)d_out;
    float* out_edges = out_nodes + (size_t)B_*CN_*S_; // packed during pipeline, f32 at end

    k_mask_norm  <<<1,    512, 0, stream>>>(mraw, ws);
    k_wprep      <<<192,  256, 0, stream>>>(We1, We2, We, ws);
    k_node_mlp_qv<<<128,  256, 0, stream>>>(nodes, Wm1, bm1, Wm2, bm2, an0, Wq, Wv, ws);
    k_qw         <<<512,  256, 0, stream>>>(ws, Wk);
    k_edge_mlp   <<<2048, 256, 0, stream>>>(edges, ws, be1, be2, ae0, (uint32_t*)out_edges);
    k_attn       <<<512,  256, 0, stream>>>((const uint32_t*)out_edges, ws);
    k_nf         <<<512,  256, 0, stream>>>(ws, Wv);
    k_node_out   <<<128,  256, 0, stream>>>(ws, Wo, We, an1, out_nodes);
    k_edge_out   <<<2048, 256, 0, stream>>>((const uint32_t*)out_edges, out_edges, ws, ae1);
}

// Round 7
// 301.345 us; speedup vs baseline: 1.6136x; 1.0376x over previous
//
#include <hip/hip_runtime.h>
#include <hip/hip_bf16.h>
#include <cstdint>
#include <cstddef>

// ---------------- problem constants ----------------
constexpr int B_  = 2;
constexpr int S_  = 256;
constexpr int CN_ = 256;
constexpr int CE_ = 128;
constexpr int A_  = 32;
constexpr int H_  = 8;
constexpr int V_  = 32;
constexpr int AH_ = A_ * H_;    // 256
constexpr int VH_ = V_ * H_;    // 256
constexpr int SS_ = S_ * S_;    // 65536
constexpr int CNE_ = CN_ + CE_; // 384

// ---------------- workspace layout (float offsets) ----------------
constexpr size_t OFF_N1   = 0;                                  // nodes1 (B,CN,S)
constexpr size_t OFF_Q    = OFF_N1  + (size_t)B_*CN_*S_;        // q * 1/sqrt(A) (B,AH,S)
constexpr size_t OFF_VN   = OFF_Q   + (size_t)B_*AH_*S_;        // vnode (B,VH,S)
constexpr size_t OFF_NF   = OFF_VN  + (size_t)B_*VH_*S_;        // nf (B,VH,S)
constexpr size_t OFF_WNF  = OFF_NF  + (size_t)B_*VH_*S_;        // Wnf (B,CE,S)
constexpr size_t OFF_WB1  = OFF_WNF + (size_t)B_*CE_*S_;        // We1 bf16 [o][c] (ushorts)
constexpr size_t OFF_WB2  = OFF_WB1 + 16384;                    // We2 bf16 [o][c]
constexpr size_t OFF_WBE  = OFF_WB2 + 16384;                    // We[:,256:384] bf16 [o][c]
constexpr size_t OFF_WKT  = OFF_WBE + 16384;                    // WkT f32 [a][h][c] (32768)
constexpr size_t OFF_MASK = OFF_WKT + 32768;                    // canonical f32 mask (B*S)

// ---------------- bf16 helpers ----------------
__device__ inline uint16_t f2bf(float x) {
    uint32_t u = __float_as_uint(x);
    uint32_t r = (u + 0x7fffu + ((u >> 16) & 1u)) >> 16;  // RNE
    return (uint16_t)r;
}
__device__ inline float bf2f(uint16_t h) {
    return __uint_as_float(((uint32_t)h) << 16);
}
// packed split: word = RNE-hi16<<16 | trunc-lo16 ; value ≈ hi+lo (±2^-17 rel)
__device__ inline uint32_t pack_split(float v) {
    uint32_t hi = (uint32_t)f2bf(v);
    float res = v - __uint_as_float(hi << 16);
    return (hi << 16) | (__float_as_uint(res) >> 16);
}
__device__ inline float unpack_f32(uint32_t p) {
    return __uint_as_float(p & 0xffff0000u) + __uint_as_float(p << 16);
}

typedef __attribute__((ext_vector_type(8))) short sh8;
typedef __attribute__((ext_vector_type(4))) short sh4;
typedef __attribute__((ext_vector_type(4))) float f32x4;

#define MFMA_B16(a, b, c) __builtin_amdgcn_mfma_f32_16x16x32_bf16((a), (b), (c), 0, 0, 0)

// LDS tile geometry: [j][c] bf16, row stride 136 ushorts + XOR-swizzle bits 3..5.
__device__ inline int eidx(int j, int c) {
    return (j * 136 + c) ^ (((j >> 3) & 7) << 3);
}

// 4-column GEMM micro: acc[0..3] += W[t][c] * xs[c][0..3], K=256, float4 loads.
#define GEMM4_K256(WROW, XS, A0, A1, A2, A3)                                   \
    for (int c = 0; c < 256; c += 4) {                                         \
        float4 w  = *(const float4*)((WROW) + c);                              \
        float4 x0 = *(const float4*)((XS) + (c+0)*4);                          \
        float4 x1 = *(const float4*)((XS) + (c+1)*4);                          \
        float4 x2 = *(const float4*)((XS) + (c+2)*4);                          \
        float4 x3 = *(const float4*)((XS) + (c+3)*4);                          \
        A0 = fmaf(w.x,x0.x,fmaf(w.y,x1.x,fmaf(w.z,x2.x,fmaf(w.w,x3.x,A0))));   \
        A1 = fmaf(w.x,x0.y,fmaf(w.y,x1.y,fmaf(w.z,x2.y,fmaf(w.w,x3.y,A1))));   \
        A2 = fmaf(w.x,x0.z,fmaf(w.y,x1.z,fmaf(w.z,x2.z,fmaf(w.w,x3.z,A2))));   \
        A3 = fmaf(w.x,x0.w,fmaf(w.y,x1.w,fmaf(w.z,x2.w,fmaf(w.w,x3.w,A3))));   \
    }

// ---------------- mask normalization ----------------
__global__ void k_mask_norm(const unsigned char* __restrict__ mraw,
                            float* __restrict__ ws)
{
    int t = threadIdx.x; // one block of 512 threads covers B*S
    unsigned char b1 = mraw[1], b2 = mraw[2];
    float mv;
    if (b1 == (unsigned char)1) {
        mv = mraw[t] ? 1.f : 0.f;                       // bool bytes
    } else if (b2 == (unsigned char)128) {
        mv = (((const float*)mraw)[t] != 0.f) ? 1.f : 0.f; // float32
    } else {
        mv = (((const int*)mraw)[t] != 0) ? 1.f : 0.f;  // int32
    }
    ws[OFF_MASK + t] = mv;
}

// ---------------- weight prep: bf16 copies + WkT transpose ----------------
__global__ void k_wprep(const float* __restrict__ We1_,
                        const float* __restrict__ We2_,
                        const float* __restrict__ We_,
                        const float* __restrict__ Wk_,
                        float* __restrict__ ws)
{
    int idx = blockIdx.x * 256 + threadIdx.x;   // 0..81919
    int m = idx >> 14;
    if (m < 3) {
        int r = idx & 16383;
        int o = r >> 7, c = r & 127;
        ushort* wb1 = (ushort*)(ws + OFF_WB1);
        ushort* wb2 = (ushort*)(ws + OFF_WB2);
        ushort* wbe = (ushort*)(ws + OFF_WBE);
        if (m == 0)      wb1[r] = f2bf(We1_[o*CE_ + c]);
        else if (m == 1) wb2[r] = f2bf(We2_[o*CE_ + c]);
        else             wbe[r] = f2bf(We_[o*CNE_ + CN_ + c]);
    } else {
        int r = idx - 49152;                    // 0..32767
        int a = r >> 10, h = (r >> 7) & 7, c = r & 127;
        ws[OFF_WKT + r] = Wk_[(size_t)(h*A_ + a)*CNE_ + CN_ + c];
    }
}

// ---------------- node MLP + q + vnode (fused), 4 cols/block ----------------
__global__ __launch_bounds__(256)
void k_node_mlp_qv(const float* __restrict__ nodes,
                   const float* __restrict__ Wm1, const float* __restrict__ bm1,
                   const float* __restrict__ Wm2, const float* __restrict__ bm2,
                   const float* __restrict__ an0,
                   const float* __restrict__ Wq,  const float* __restrict__ Wv,
                   float* __restrict__ ws)
{
    __shared__ float xs[CN_ * 4];
    __shared__ float hs[CN_ * 4];
    const int t  = threadIdx.x;
    const int b  = blockIdx.x >> 6;           // 64 blocks per batch
    const int s0 = (blockIdx.x & 63) * 4;

    {
        float4 nv = *(const float4*)(nodes + (size_t)(b*CN_+t)*S_ + s0);
        xs[t*4+0]=nv.x; xs[t*4+1]=nv.y; xs[t*4+2]=nv.z; xs[t*4+3]=nv.w;
    }
    __syncthreads();

    float a0, a1, a2, a3;
    { // layer 1
        float bv = bm1[t]; a0=bv; a1=bv; a2=bv; a3=bv;
        GEMM4_K256(Wm1 + t*CN_, xs, a0, a1, a2, a3);
        hs[t*4+0]=fmaxf(a0,0.f); hs[t*4+1]=fmaxf(a1,0.f);
        hs[t*4+2]=fmaxf(a2,0.f); hs[t*4+3]=fmaxf(a3,0.f);
    }
    __syncthreads();
    { // layer 2
        float bv = bm2[t]; a0=bv; a1=bv; a2=bv; a3=bv;
        GEMM4_K256(Wm2 + t*CN_, hs, a0, a1, a2, a3);
    }
    { // ReZero residual -> nodes1
        float an = an0[t];
        float n0 = xs[t*4+0] + an*fmaxf(a0,0.f);
        float n1 = xs[t*4+1] + an*fmaxf(a1,0.f);
        float n2 = xs[t*4+2] + an*fmaxf(a2,0.f);
        float n3 = xs[t*4+3] + an*fmaxf(a3,0.f);
        xs[t*4+0]=n0; xs[t*4+1]=n1; xs[t*4+2]=n2; xs[t*4+3]=n3;
        *(float4*)(ws + OFF_N1 + (size_t)(b*CN_+t)*S_ + s0) = make_float4(n0,n1,n2,n3);
    }
    __syncthreads();

    { // q (1/sqrt(A) folded)
        a0=0.f; a1=0.f; a2=0.f; a3=0.f;
        GEMM4_K256(Wq + t*CN_, xs, a0, a1, a2, a3);
        const float rsA = 0.1767766952966369f;
        *(float4*)(ws + OFF_Q + (size_t)(b*AH_+t)*S_ + s0) =
            make_float4(a0*rsA, a1*rsA, a2*rsA, a3*rsA);
    }
    { // vnode = Wv[:, :CN] @ nodes1
        a0=0.f; a1=0.f; a2=0.f; a3=0.f;
        GEMM4_K256(Wv + t*CNE_, xs, a0, a1, a2, a3);
        *(float4*)(ws + OFF_VN + (size_t)(b*VH_+t)*S_ + s0) = make_float4(a0,a1,a2,a3);
    }
}

// ---------------- edge MLP: hi-only MFMA; OUTPUT = packed RNE-hi|lo u32 ----------------
__global__ __launch_bounds__(256, 2)
void k_edge_mlp(const float* __restrict__ edges,
                const float* __restrict__ ws,
                const float* __restrict__ be1, const float* __restrict__ be2,
                const float* __restrict__ ae0,
                uint32_t* __restrict__ e1out)
{
    __shared__ ushort Ehi[64 * 136];
    __shared__ ushort Elo[64 * 136];
    __shared__ ushort Ht [64 * 136];

    const int t  = threadIdx.x;
    const int b  = blockIdx.x >> 10;
    const int i  = (blockIdx.x >> 2) & 255;
    const int j0 = (blockIdx.x & 3) * 64;
    const float* Eb = edges + (size_t)b*CE_*SS_ + (size_t)i*S_ + j0;

    // ---- stage: RNE hi (MFMA input + residual), trunc lo (residual only) ----
    {
        const int tj = t & 15;
        const int p0 = t >> 4;
        #pragma unroll
        for (int s = 0; s < 4; ++s) {
            int c = (s*16 + p0) * 2;
            float4 v0 = *(const float4*)(Eb + (size_t)c*SS_ + tj*4);
            float4 v1 = *(const float4*)(Eb + (size_t)(c+1)*SS_ + tj*4);
            float q0[4] = {v0.x, v0.y, v0.z, v0.w};
            float q1[4] = {v1.x, v1.y, v1.z, v1.w};
            #pragma unroll
            for (int jj = 0; jj < 4; ++jj) {
                int j = tj*4 + jj;
                uint32_t h0 = (uint32_t)f2bf(q0[jj]);
                uint32_t h1 = (uint32_t)f2bf(q1[jj]);
                float r0 = q0[jj] - __uint_as_float(h0 << 16);
                float r1 = q1[jj] - __uint_as_float(h1 << 16);
                int us = eidx(j, c);
                *(uint32_t*)&Ehi[us] = h0 | (h1 << 16);
                *(uint32_t*)&Elo[us] = (__float_as_uint(r0) >> 16)
                                     | (__float_as_uint(r1) & 0xffff0000u);
            }
        }
    }

    // ---- preload A fragments ----
    const int w  = t >> 6;
    const int l  = t & 63;
    const int lr = l & 15;
    const int lk = l >> 4;
    const ushort* wb1 = (const ushort*)(ws + OFF_WB1);
    const ushort* wb2 = (const ushort*)(ws + OFF_WB2);
    sh8 A1[2][4], A2[2][4];
    #pragma unroll
    for (int mt = 0; mt < 2; ++mt) {
        int o = w*32 + mt*16 + lr;
        #pragma unroll
        for (int ks = 0; ks < 4; ++ks) {
            A1[mt][ks] = *(const sh8*)(wb1 + o*CE_ + ks*32 + lk*8);
            A2[mt][ks] = *(const sh8*)(wb2 + o*CE_ + ks*32 + lk*8);
        }
    }

    // ---- layer 1 (hi-only) ----
    f32x4 acc1[2][4];
    #pragma unroll
    for (int mt = 0; mt < 2; ++mt) {
        float4 bv = *(const float4*)(be1 + w*32 + mt*16 + lk*4);
        #pragma unroll
        for (int nt = 0; nt < 4; ++nt) {
            acc1[mt][nt][0] = bv.x; acc1[mt][nt][1] = bv.y;
            acc1[mt][nt][2] = bv.z; acc1[mt][nt][3] = bv.w;
        }
    }
    __syncthreads();
    #pragma unroll
    for (int nt = 0; nt < 4; ++nt) {
        int j = nt*16 + lr;
        sh8 bh[4];
        #pragma unroll
        for (int ks = 0; ks < 4; ++ks)
            bh[ks] = *(const sh8*)&Ehi[eidx(j, ks*32 + lk*8)];
        #pragma unroll
        for (int mt = 0; mt < 2; ++mt)
            #pragma unroll
            for (int ks = 0; ks < 4; ++ks)
                acc1[mt][nt] = MFMA_B16(A1[mt][ks], bh[ks], acc1[mt][nt]);
    }

    // ---- h = relu -> bf16 (trunc) -> Ht ----
    #pragma unroll
    for (int mt = 0; mt < 2; ++mt)
        #pragma unroll
        for (int nt = 0; nt < 4; ++nt) {
            int o0 = w*32 + mt*16 + lk*4;
            int j  = nt*16 + lr;
            uint32_t u0 = __float_as_uint(fmaxf(acc1[mt][nt][0], 0.f));
            uint32_t u1 = __float_as_uint(fmaxf(acc1[mt][nt][1], 0.f));
            uint32_t u2 = __float_as_uint(fmaxf(acc1[mt][nt][2], 0.f));
            uint32_t u3 = __float_as_uint(fmaxf(acc1[mt][nt][3], 0.f));
            int us = eidx(j, o0);
            *(uint32_t*)&Ht[us]     = (u0 >> 16) | (u1 & 0xffff0000u);
            *(uint32_t*)&Ht[us + 2] = (u2 >> 16) | (u3 & 0xffff0000u);
        }
    __syncthreads();

    // ---- layer 2 ----
    f32x4 acc2[2][4];
    #pragma unroll
    for (int mt = 0; mt < 2; ++mt) {
        float4 bv = *(const float4*)(be2 + w*32 + mt*16 + lk*4);
        #pragma unroll
        for (int nt = 0; nt < 4; ++nt) {
            acc2[mt][nt][0] = bv.x; acc2[mt][nt][1] = bv.y;
            acc2[mt][nt][2] = bv.z; acc2[mt][nt][3] = bv.w;
        }
    }
    #pragma unroll
    for (int nt = 0; nt < 4; ++nt) {
        int j = nt*16 + lr;
        sh8 hh[4];
        #pragma unroll
        for (int ks = 0; ks < 4; ++ks)
            hh[ks] = *(const sh8*)&Ht[eidx(j, ks*32 + lk*8)];
        #pragma unroll
        for (int mt = 0; mt < 2; ++mt)
            #pragma unroll
            for (int ks = 0; ks < 4; ++ks)
                acc2[mt][nt] = MFMA_B16(A2[mt][ks], hh[ks], acc2[mt][nt]);
    }

    // ---- epilogue: edges1 = (Ehi+Elo) + ae0*relu(acc2), store PACKED ----
    #pragma unroll
    for (int mt = 0; mt < 2; ++mt) {
        int o0 = w*32 + mt*16 + lk*4;
        float4 a0v = *(const float4*)(ae0 + o0);
        float aev[4] = {a0v.x, a0v.y, a0v.z, a0v.w};
        #pragma unroll
        for (int nt = 0; nt < 4; ++nt) {
            int j = nt*16 + lr;
            int us = eidx(j, o0);
            sh4 eh = *(const sh4*)&Ehi[us];
            sh4 el = *(const sh4*)&Elo[us];
            #pragma unroll
            for (int r = 0; r < 4; ++r) {
                float e = bf2f((uint16_t)eh[r]) + bf2f((uint16_t)el[r]);
                float g = fmaxf(acc2[mt][nt][r], 0.f);
                e1out[(size_t)(b*CE_ + o0 + r)*SS_ + (size_t)i*S_ + j0 + j] =
                    pack_split(e + aev[r]*g);
            }
        }
    }
}

// ---------------- fused attention: qw + sim + softmax + se + nf ----------------
__global__ __launch_bounds__(256)
void k_attn(const uint32_t* __restrict__ e1, float* __restrict__ ws,
            const float* __restrict__ Wv)
{
    __shared__ float qcol[AH_];
    __shared__ float qw[CE_ * 8];      // [c'][h]
    __shared__ float simL[H_ * S_];    // 8 x 256
    __shared__ float Etile[CE_ * 65];
    __shared__ float seL[1024];        // [h][c']
    const int t = threadIdx.x;
    const int b = blockIdx.x >> 8, i = blockIdx.x & 255;
    const float* maskf = ws + OFF_MASK;

    qcol[t] = ws[OFF_Q + (size_t)(b*AH_+t)*S_ + i];
    __syncthreads();

    { // qw phase: coalesced WkT[a][h][c] reads
        const float* WkT = ws + OFF_WKT;
        #pragma unroll
        for (int k = 0; k < 4; ++k) {
            int idx = k*256 + t;
            int c = idx & 127, h = idx >> 7;
            float acc = 0.f;
            #pragma unroll 8
            for (int aa = 0; aa < A_; ++aa)
                acc = fmaf(qcol[h*A_ + aa], WkT[aa*1024 + h*128 + c], acc);
            qw[c*8 + h] = acc;
        }
    }
    __syncthreads();

    const uint32_t* Eb = e1 + ((size_t)(b*CE_)*S_ + i)*S_;
    float sv[8];
    #pragma unroll
    for (int h = 0; h < 8; ++h) sv[h] = 0.f;
    for (int c = 0; c < CE_; ++c) {
        float e = unpack_f32(Eb[(size_t)c*SS_ + t]);
        float4 q0 = *(const float4*)(qw + c*8);
        float4 q1 = *(const float4*)(qw + c*8 + 4);
        sv[0] = fmaf(q0.x, e, sv[0]); sv[1] = fmaf(q0.y, e, sv[1]);
        sv[2] = fmaf(q0.z, e, sv[2]); sv[3] = fmaf(q0.w, e, sv[3]);
        sv[4] = fmaf(q1.x, e, sv[4]); sv[5] = fmaf(q1.y, e, sv[5]);
        sv[6] = fmaf(q1.z, e, sv[6]); sv[7] = fmaf(q1.w, e, sv[7]);
    }
    const bool mj = maskf[b*S_ + t] != 0.f;
    #pragma unroll
    for (int h = 0; h < 8; ++h) simL[h*S_ + t] = mj ? sv[h] : -1e9f;
    __syncthreads();

    { // masked softmax per head
        const int h = t >> 5, l = t & 31;
        float vv[8]; float m = -3.4e38f;
        #pragma unroll
        for (int k = 0; k < 8; ++k) { vv[k] = simL[h*S_ + l + k*32]; m = fmaxf(m, vv[k]); }
        #pragma unroll
        for (int off = 16; off >= 1; off >>= 1) m = fmaxf(m, __shfl_xor(m, off, 32));
        float ssum = 0.f; float ex[8];
        #pragma unroll
        for (int k = 0; k < 8; ++k) { ex[k] = __expf(vv[k] - m); ssum += ex[k]; }
        #pragma unroll
        for (int off = 16; off >= 1; off >>= 1) ssum += __shfl_xor(ssum, off, 32);
        const float mi = maskf[b*S_ + i];
        const float rr = mi / ssum;
        #pragma unroll
        for (int k = 0; k < 8; ++k) simL[h*S_ + l + k*32] = ex[k] * rr;
    }
    __syncthreads();

    // se[h][c'] = sum_j sim[h][j] * E1[c'][i][j]
    const int cp = t & 127, hg = t >> 7;
    float a4[4] = {0.f, 0.f, 0.f, 0.f};
    for (int jt = 0; jt < 4; ++jt) {
        #pragma unroll 4
        for (int r = 0; r < 32; ++r) {
            int idx = r*256 + t;
            int c = idx >> 6, j = idx & 63;
            Etile[c*65 + j] = unpack_f32(Eb[(size_t)c*SS_ + jt*64 + j]);
        }
        __syncthreads();
        for (int j = 0; j < 64; ++j) {
            float e = Etile[cp*65 + j];
            #pragma unroll
            for (int k = 0; k < 4; ++k)
                a4[k] = fmaf(e, simL[(hg*4+k)*S_ + jt*64 + j], a4[k]);
        }
        __syncthreads();
    }
    #pragma unroll
    for (int k = 0; k < 4; ++k) seL[(hg*4+k)*128 + cp] = a4[k];
    __syncthreads();

    { // nf phase (was k_nf): nf = vnode*mi + Wv_edge @ se
        const int h2 = t >> 5;
        float acc = 0.f;
        const float* wvr = Wv + (size_t)t*CNE_ + CN_;
        for (int c = 0; c < CE_; c += 4) {
            float4 wv4 = *(const float4*)(wvr + c);
            acc = fmaf(wv4.x, seL[h2*128 + c],     acc);
            acc = fmaf(wv4.y, seL[h2*128 + c + 1], acc);
            acc = fmaf(wv4.z, seL[h2*128 + c + 2], acc);
            acc = fmaf(wv4.w, seL[h2*128 + c + 3], acc);
        }
        const float mi = maskf[b*S_ + i];
        float nfv = ws[OFF_VN + (size_t)(b*VH_+t)*S_ + i] * mi + acc;
        ws[OFF_NF + (size_t)(b*VH_+t)*S_ + i] = nfv;
    }
}

// ---------------- node output + Wnf, 4 cols/block ----------------
__global__ __launch_bounds__(256)
void k_node_out(float* __restrict__ ws, const float* __restrict__ Wo,
                const float* __restrict__ We, const float* __restrict__ an1,
                float* __restrict__ out_nodes)
{
    __shared__ float xs[VH_ * 4];
    const int t  = threadIdx.x;
    const int b  = blockIdx.x >> 6;
    const int s0 = (blockIdx.x & 63) * 4;
    {
        float4 nv = *(const float4*)(ws + OFF_NF + (size_t)(b*VH_+t)*S_ + s0);
        xs[t*4+0]=nv.x; xs[t*4+1]=nv.y; xs[t*4+2]=nv.z; xs[t*4+3]=nv.w;
    }
    __syncthreads();
    float a0=0.f, a1=0.f, a2=0.f, a3=0.f;
    GEMM4_K256(Wo + t*VH_, xs, a0, a1, a2, a3);
    {
        float aw = an1[t];
        float4 n1 = *(const float4*)(ws + OFF_N1 + (size_t)(b*CN_+t)*S_ + s0);
        float4 mk = *(const float4*)(ws + OFF_MASK + b*S_ + s0);
        *(float4*)(out_nodes + (size_t)(b*CN_+t)*S_ + s0) = make_float4(
            (n1.x + aw*a0) * mk.x, (n1.y + aw*a1) * mk.y,
            (n1.z + aw*a2) * mk.z, (n1.w + aw*a3) * mk.w);
    }
    if (t < CE_) { // Wnf = We[:, :VH] @ nf
        a0=0.f; a1=0.f; a2=0.f; a3=0.f;
        GEMM4_K256(We + t*CNE_, xs, a0, a1, a2, a3);
        *(float4*)(ws + OFF_WNF + (size_t)(b*CE_+t)*S_ + s0) = make_float4(a0,a1,a2,a3);
    }
}

// ---------------- edge output: hi-only MFMA (packed in, f32 out, in-place) ----------------
__global__ __launch_bounds__(256, 2)
void k_edge_out(const uint32_t* __restrict__ e1p, float* __restrict__ e1f,
                const float* __restrict__ ws, const float* __restrict__ ae1)
{
    __shared__ ushort Ehi[64 * 136];
    __shared__ ushort Elo[64 * 136];
    __shared__ float  wni_s[CE_];

    const int t  = threadIdx.x;
    const int b  = blockIdx.x >> 10;
    const int i  = (blockIdx.x >> 2) & 255;
    const int j0 = (blockIdx.x & 3) * 64;
    const uint32_t* Ebp = e1p + (size_t)b*CE_*SS_ + (size_t)i*S_ + j0;
    float*          Ebf = e1f + (size_t)b*CE_*SS_ + (size_t)i*S_ + j0;
    const float* Wnf   = ws + OFF_WNF;
    const float* maskf = ws + OFF_MASK;

    if (t < CE_) wni_s[t] = Wnf[(size_t)(b*CE_ + t)*S_ + i];

    // ---- stage: bit-split packed words into hi/lo LDS ----
    {
        const int tj = t & 15;
        const int p0 = t >> 4;
        #pragma unroll
        for (int s = 0; s < 4; ++s) {
            int c = (s*16 + p0) * 2;
            uint4 v0 = *(const uint4*)(Ebp + (size_t)c*SS_ + tj*4);
            uint4 v1 = *(const uint4*)(Ebp + (size_t)(c+1)*SS_ + tj*4);
            uint32_t w0[4] = {v0.x, v0.y, v0.z, v0.w};
            uint32_t w1[4] = {v1.x, v1.y, v1.z, v1.w};
            #pragma unroll
            for (int jj = 0; jj < 4; ++jj) {
                int j = tj*4 + jj;
                int us = eidx(j, c);
                *(uint32_t*)&Ehi[us] = (w0[jj] >> 16) | (w1[jj] & 0xffff0000u);
                *(uint32_t*)&Elo[us] = (w0[jj] & 0xffffu) | (w1[jj] << 16);
            }
        }
    }

    const int w  = t >> 6;
    const int l  = t & 63;
    const int lr = l & 15;
    const int lk = l >> 4;
    const ushort* wbe = (const ushort*)(ws + OFF_WBE);
    sh8 AE[2][4];
    #pragma unroll
    for (int mt = 0; mt < 2; ++mt) {
        int o = w*32 + mt*16 + lr;
        #pragma unroll
        for (int ks = 0; ks < 4; ++ks)
            AE[mt][ks] = *(const sh8*)(wbe + o*CE_ + ks*32 + lk*8);
    }

    f32x4 acc[2][4];
    #pragma unroll
    for (int mt = 0; mt < 2; ++mt)
        #pragma unroll
        for (int nt = 0; nt < 4; ++nt)
            acc[mt][nt] = (f32x4){0.f, 0.f, 0.f, 0.f};
    __syncthreads();
    #pragma unroll
    for (int nt = 0; nt < 4; ++nt) {
        int j = nt*16 + lr;
        sh8 bh[4];
        #pragma unroll
        for (int ks = 0; ks < 4; ++ks)
            bh[ks] = *(const sh8*)&Ehi[eidx(j, ks*32 + lk*8)];
        #pragma unroll
        for (int mt = 0; mt < 2; ++mt)
            #pragma unroll
            for (int ks = 0; ks < 4; ++ks)
                acc[mt][nt] = MFMA_B16(AE[mt][ks], bh[ks], acc[mt][nt]);
    }

    // ---- epilogue ----
    const float mi = maskf[b*S_ + i];
    #pragma unroll
    for (int mt = 0; mt < 2; ++mt) {
        int o0 = w*32 + mt*16 + lk*4;
        float4 a1v = *(const float4*)(ae1 + o0);
        float aev[4] = {a1v.x, a1v.y, a1v.z, a1v.w};
        #pragma unroll
        for (int nt = 0; nt < 4; ++nt) {
            int j  = nt*16 + lr;
            int jg = j0 + j;
            float mjv = maskf[b*S_ + jg];
            int us = eidx(j, o0);
            sh4 eh = *(const sh4*)&Ehi[us];
            sh4 el = *(const sh4*)&Elo[us];
            #pragma unroll
            for (int r = 0; r < 4; ++r) {
                float e   = bf2f((uint16_t)eh[r]) + bf2f((uint16_t)el[r]);
                float att = 0.5f*(wni_s[o0+r] + Wnf[(size_t)(b*CE_+o0+r)*S_ + jg])
                          + acc[mt][nt][r];
                Ebf[(size_t)(o0+r)*SS_ + j] = (e + aev[r]*att) * (mi * mjv);
            }
        }
    }
}

// ---------------- launch ----------------
extern "C" void kernel_launch(void* const* d_in, const int* in_sizes, int n_in,
                              void* d_out, int out_size, void* d_ws, size_t ws_size,
                              hipStream_t stream)
{
    const float* nodes = (const float*)d_in[0];
    const float* edges = (const float*)d_in[1];
    const unsigned char* mraw = (const unsigned char*)d_in[2];
    const float* Wq  = (const float*)d_in[3];
    const float* Wk  = (const float*)d_in[4];
    const float* Wv  = (const float*)d_in[5];
    const float* Wo  = (const float*)d_in[6];
    const float* We  = (const float*)d_in[7];
    const float* Wm1 = (const float*)d_in[8];
    const float* bm1 = (const float*)d_in[9];
    const float* Wm2 = (const float*)d_in[10];
    const float* bm2 = (const float*)d_in[11];
    const float* We1 = (const float*)d_in[12];
    const float* be1 = (const float*)d_in[13];
    const float* We2 = (const float*)d_in[14];
    const float* be2 = (const float*)d_in[15];
    const float* an0 = (const float*)d_in[16];
    const float* an1 = (const float*)d_in[17];
    const float* ae0 = (const float*)d_in[18];
    const float* ae1 = (const float*)d_in[19];

    float* ws = (float*)d_ws;
    float* out_nodes = (float*)d_out;
    float* out_edges = out_nodes + (size_t)B_*CN_*S_; // packed during pipeline, f32 at end

    k_mask_norm  <<<1,    512, 0, stream>>>(mraw, ws);
    k_wprep      <<<320,  256, 0, stream>>>(We1, We2, We, Wk, ws);
    k_node_mlp_qv<<<128,  256, 0, stream>>>(nodes, Wm1, bm1, Wm2, bm2, an0, Wq, Wv, ws);
    k_edge_mlp   <<<2048, 256, 0, stream>>>(edges, ws, be1, be2, ae0, (uint32_t*)out_edges);
    k_attn       <<<512,  256, 0, stream>>>((const uint32_t*)out_edges, ws, Wv);
    k_node_out   <<<128,  256, 0, stream>>>(ws, Wo, We, an1, out_nodes);
    k_edge_out   <<<2048, 256, 0, stream>>>((const uint32_t*)out_edges, out_edges, ws, ae1);
}

// Round 14
// 292.215 us; speedup vs baseline: 1.6640x; 1.0312x over previous
//
#include <hip/hip_runtime.h>
#include <hip/hip_bf16.h>
#include <cstdint>
#include <cstddef>

// ---------------- problem constants ----------------
constexpr int B_  = 2;
constexpr int S_  = 256;
constexpr int CN_ = 256;
constexpr int CE_ = 128;
constexpr int A_  = 32;
constexpr int H_  = 8;
constexpr int V_  = 32;
constexpr int AH_ = A_ * H_;    // 256
constexpr int VH_ = V_ * H_;    // 256
constexpr int SS_ = S_ * S_;    // 65536
constexpr int CNE_ = CN_ + CE_; // 384

// ---------------- workspace layout (float offsets) ----------------
constexpr size_t OFF_N1   = 0;                                  // nodes1 (B,CN,S)
constexpr size_t OFF_Q    = OFF_N1  + (size_t)B_*CN_*S_;        // q * 1/sqrt(A) (B,AH,S)
constexpr size_t OFF_VN   = OFF_Q   + (size_t)B_*AH_*S_;        // vnode (B,VH,S)
constexpr size_t OFF_NF   = OFF_VN  + (size_t)B_*VH_*S_;        // nf (B,VH,S)
constexpr size_t OFF_WNF  = OFF_NF  + (size_t)B_*VH_*S_;        // Wnf (B,CE,S)
constexpr size_t OFF_WB1  = OFF_WNF + (size_t)B_*CE_*S_;        // We1 bf16 [o][c] (ushorts)
constexpr size_t OFF_WB2  = OFF_WB1 + 16384;                    // We2 bf16 [o][c]
constexpr size_t OFF_WBE  = OFF_WB2 + 16384;                    // We[:,256:384] bf16 [o][c]
constexpr size_t OFF_WKT  = OFF_WBE + 16384;                    // WkT f32 [a][h][c] (32768)
constexpr size_t OFF_WVT  = OFF_WKT + 32768;                    // WvT f32 [c][o]   (32768)
constexpr size_t OFF_MASK = OFF_WVT + 32768;                    // canonical f32 mask (B*S)

// ---------------- bf16 helpers ----------------
__device__ inline uint16_t f2bf(float x) {
    uint32_t u = __float_as_uint(x);
    uint32_t r = (u + 0x7fffu + ((u >> 16) & 1u)) >> 16;  // RNE
    return (uint16_t)r;
}
__device__ inline float bf2f(uint16_t h) {
    return __uint_as_float(((uint32_t)h) << 16);
}
// packed split: word = RNE-hi16<<16 | trunc-lo16 ; value ≈ hi+lo (±2^-17 rel)
__device__ inline uint32_t pack_split(float v) {
    uint32_t hi = (uint32_t)f2bf(v);
    float res = v - __uint_as_float(hi << 16);
    return (hi << 16) | (__float_as_uint(res) >> 16);
}
__device__ inline float unpack_f32(uint32_t p) {
    return __uint_as_float(p & 0xffff0000u) + __uint_as_float(p << 16);
}

typedef __attribute__((ext_vector_type(8))) short sh8;
typedef __attribute__((ext_vector_type(4))) short sh4;
typedef __attribute__((ext_vector_type(4))) float f32x4;

#define MFMA_B16(a, b, c) __builtin_amdgcn_mfma_f32_16x16x32_bf16((a), (b), (c), 0, 0, 0)

// LDS tile geometry: [j][c] bf16, row stride 136 ushorts + XOR-swizzle bits 3..5.
__device__ inline int eidx(int j, int c) {
    return (j * 136 + c) ^ (((j >> 3) & 7) << 3);
}

// 4-column GEMM micro: acc[0..3] += W[t][c] * xs[c][0..3], K=256, float4 loads.
#define GEMM4_K256(WROW, XS, A0, A1, A2, A3)                                   \
    for (int c = 0; c < 256; c += 4) {                                         \
        float4 w  = *(const float4*)((WROW) + c);                              \
        float4 x0 = *(const float4*)((XS) + (c+0)*4);                          \
        float4 x1 = *(const float4*)((XS) + (c+1)*4);                          \
        float4 x2 = *(const float4*)((XS) + (c+2)*4);                          \
        float4 x3 = *(const float4*)((XS) + (c+3)*4);                          \
        A0 = fmaf(w.x,x0.x,fmaf(w.y,x1.x,fmaf(w.z,x2.x,fmaf(w.w,x3.x,A0))));   \
        A1 = fmaf(w.x,x0.y,fmaf(w.y,x1.y,fmaf(w.z,x2.y,fmaf(w.w,x3.y,A1))));   \
        A2 = fmaf(w.x,x0.z,fmaf(w.y,x1.z,fmaf(w.z,x2.z,fmaf(w.w,x3.z,A2))));   \
        A3 = fmaf(w.x,x0.w,fmaf(w.y,x1.w,fmaf(w.z,x2.w,fmaf(w.w,x3.w,A3))));   \
    }

// ---------------- mask normalization ----------------
__global__ void k_mask_norm(const unsigned char* __restrict__ mraw,
                            float* __restrict__ ws)
{
    int t = threadIdx.x; // one block of 512 threads covers B*S
    unsigned char b1 = mraw[1], b2 = mraw[2];
    float mv;
    if (b1 == (unsigned char)1) {
        mv = mraw[t] ? 1.f : 0.f;                       // bool bytes
    } else if (b2 == (unsigned char)128) {
        mv = (((const float*)mraw)[t] != 0.f) ? 1.f : 0.f; // float32
    } else {
        mv = (((const int*)mraw)[t] != 0) ? 1.f : 0.f;  // int32
    }
    ws[OFF_MASK + t] = mv;
}

// ---------------- weight prep: bf16 copies + WkT + WvT transposes ----------------
__global__ void k_wprep(const float* __restrict__ We1_,
                        const float* __restrict__ We2_,
                        const float* __restrict__ We_,
                        const float* __restrict__ Wk_,
                        const float* __restrict__ Wv_,
                        float* __restrict__ ws)
{
    int idx = blockIdx.x * 256 + threadIdx.x;   // 0..114687
    if (idx < 49152) {
        int m = idx >> 14;
        int r = idx & 16383;
        int o = r >> 7, c = r & 127;
        ushort* wb1 = (ushort*)(ws + OFF_WB1);
        ushort* wb2 = (ushort*)(ws + OFF_WB2);
        ushort* wbe = (ushort*)(ws + OFF_WBE);
        if (m == 0)      wb1[r] = f2bf(We1_[o*CE_ + c]);
        else if (m == 1) wb2[r] = f2bf(We2_[o*CE_ + c]);
        else             wbe[r] = f2bf(We_[o*CNE_ + CN_ + c]);
    } else if (idx < 81920) {
        int r = idx - 49152;                    // 0..32767  WkT[a][h][c]
        int a = r >> 10, h = (r >> 7) & 7, c = r & 127;
        ws[OFF_WKT + r] = Wk_[(size_t)(h*A_ + a)*CNE_ + CN_ + c];
    } else {
        int r = idx - 81920;                    // 0..32767  WvT[c][o]
        int c = r >> 8, o = r & 255;
        ws[OFF_WVT + r] = Wv_[(size_t)o*CNE_ + CN_ + c];
    }
}

// ---------------- node MLP + q + vnode (fused), 4 cols/block ----------------
__global__ __launch_bounds__(256)
void k_node_mlp_qv(const float* __restrict__ nodes,
                   const float* __restrict__ Wm1, const float* __restrict__ bm1,
                   const float* __restrict__ Wm2, const float* __restrict__ bm2,
                   const float* __restrict__ an0,
                   const float* __restrict__ Wq,  const float* __restrict__ Wv,
                   float* __restrict__ ws)
{
    __shared__ float xs[CN_ * 4];
    __shared__ float hs[CN_ * 4];
    const int t  = threadIdx.x;
    const int b  = blockIdx.x >> 6;           // 64 blocks per batch
    const int s0 = (blockIdx.x & 63) * 4;

    {
        float4 nv = *(const float4*)(nodes + (size_t)(b*CN_+t)*S_ + s0);
        xs[t*4+0]=nv.x; xs[t*4+1]=nv.y; xs[t*4+2]=nv.z; xs[t*4+3]=nv.w;
    }
    __syncthreads();

    float a0, a1, a2, a3;
    { // layer 1
        float bv = bm1[t]; a0=bv; a1=bv; a2=bv; a3=bv;
        GEMM4_K256(Wm1 + t*CN_, xs, a0, a1, a2, a3);
        hs[t*4+0]=fmaxf(a0,0.f); hs[t*4+1]=fmaxf(a1,0.f);
        hs[t*4+2]=fmaxf(a2,0.f); hs[t*4+3]=fmaxf(a3,0.f);
    }
    __syncthreads();
    { // layer 2
        float bv = bm2[t]; a0=bv; a1=bv; a2=bv; a3=bv;
        GEMM4_K256(Wm2 + t*CN_, hs, a0, a1, a2, a3);
    }
    { // ReZero residual -> nodes1
        float an = an0[t];
        float n0 = xs[t*4+0] + an*fmaxf(a0,0.f);
        float n1 = xs[t*4+1] + an*fmaxf(a1,0.f);
        float n2 = xs[t*4+2] + an*fmaxf(a2,0.f);
        float n3 = xs[t*4+3] + an*fmaxf(a3,0.f);
        xs[t*4+0]=n0; xs[t*4+1]=n1; xs[t*4+2]=n2; xs[t*4+3]=n3;
        *(float4*)(ws + OFF_N1 + (size_t)(b*CN_+t)*S_ + s0) = make_float4(n0,n1,n2,n3);
    }
    __syncthreads();

    { // q (1/sqrt(A) folded)
        a0=0.f; a1=0.f; a2=0.f; a3=0.f;
        GEMM4_K256(Wq + t*CN_, xs, a0, a1, a2, a3);
        const float rsA = 0.1767766952966369f;
        *(float4*)(ws + OFF_Q + (size_t)(b*AH_+t)*S_ + s0) =
            make_float4(a0*rsA, a1*rsA, a2*rsA, a3*rsA);
    }
    { // vnode = Wv[:, :CN] @ nodes1
        a0=0.f; a1=0.f; a2=0.f; a3=0.f;
        GEMM4_K256(Wv + t*CNE_, xs, a0, a1, a2, a3);
        *(float4*)(ws + OFF_VN + (size_t)(b*VH_+t)*S_ + s0) = make_float4(a0,a1,a2,a3);
    }
}

// ---------------- edge MLP: hi-only MFMA; OUTPUT = packed RNE-hi|lo u32 ----------------
__global__ __launch_bounds__(256, 2)
void k_edge_mlp(const float* __restrict__ edges,
                const float* __restrict__ ws,
                const float* __restrict__ be1, const float* __restrict__ be2,
                const float* __restrict__ ae0,
                uint32_t* __restrict__ e1out)
{
    __shared__ ushort Ehi[64 * 136];
    __shared__ ushort Elo[64 * 136];
    __shared__ ushort Ht [64 * 136];

    const int t  = threadIdx.x;
    const int b  = blockIdx.x >> 10;
    const int i  = (blockIdx.x >> 2) & 255;
    const int j0 = (blockIdx.x & 3) * 64;
    const float* Eb = edges + (size_t)b*CE_*SS_ + (size_t)i*S_ + j0;

    // ---- stage: RNE hi (MFMA input + residual), trunc lo (residual only) ----
    {
        const int tj = t & 15;
        const int p0 = t >> 4;
        #pragma unroll
        for (int s = 0; s < 4; ++s) {
            int c = (s*16 + p0) * 2;
            float4 v0 = *(const float4*)(Eb + (size_t)c*SS_ + tj*4);
            float4 v1 = *(const float4*)(Eb + (size_t)(c+1)*SS_ + tj*4);
            float q0[4] = {v0.x, v0.y, v0.z, v0.w};
            float q1[4] = {v1.x, v1.y, v1.z, v1.w};
            #pragma unroll
            for (int jj = 0; jj < 4; ++jj) {
                int j = tj*4 + jj;
                uint32_t h0 = (uint32_t)f2bf(q0[jj]);
                uint32_t h1 = (uint32_t)f2bf(q1[jj]);
                float r0 = q0[jj] - __uint_as_float(h0 << 16);
                float r1 = q1[jj] - __uint_as_float(h1 << 16);
                int us = eidx(j, c);
                *(uint32_t*)&Ehi[us] = h0 | (h1 << 16);
                *(uint32_t*)&Elo[us] = (__float_as_uint(r0) >> 16)
                                     | (__float_as_uint(r1) & 0xffff0000u);
            }
        }
    }

    // ---- preload A fragments ----
    const int w  = t >> 6;
    const int l  = t & 63;
    const int lr = l & 15;
    const int lk = l >> 4;
    const ushort* wb1 = (const ushort*)(ws + OFF_WB1);
    const ushort* wb2 = (const ushort*)(ws + OFF_WB2);
    sh8 A1[2][4], A2[2][4];
    #pragma unroll
    for (int mt = 0; mt < 2; ++mt) {
        int o = w*32 + mt*16 + lr;
        #pragma unroll
        for (int ks = 0; ks < 4; ++ks) {
            A1[mt][ks] = *(const sh8*)(wb1 + o*CE_ + ks*32 + lk*8);
            A2[mt][ks] = *(const sh8*)(wb2 + o*CE_ + ks*32 + lk*8);
        }
    }

    // ---- layer 1 (hi-only) ----
    f32x4 acc1[2][4];
    #pragma unroll
    for (int mt = 0; mt < 2; ++mt) {
        float4 bv = *(const float4*)(be1 + w*32 + mt*16 + lk*4);
        #pragma unroll
        for (int nt = 0; nt < 4; ++nt) {
            acc1[mt][nt][0] = bv.x; acc1[mt][nt][1] = bv.y;
            acc1[mt][nt][2] = bv.z; acc1[mt][nt][3] = bv.w;
        }
    }
    __syncthreads();
    #pragma unroll
    for (int nt = 0; nt < 4; ++nt) {
        int j = nt*16 + lr;
        sh8 bh[4];
        #pragma unroll
        for (int ks = 0; ks < 4; ++ks)
            bh[ks] = *(const sh8*)&Ehi[eidx(j, ks*32 + lk*8)];
        #pragma unroll
        for (int mt = 0; mt < 2; ++mt)
            #pragma unroll
            for (int ks = 0; ks < 4; ++ks)
                acc1[mt][nt] = MFMA_B16(A1[mt][ks], bh[ks], acc1[mt][nt]);
    }

    // ---- h = relu -> bf16 (trunc) -> Ht ----
    #pragma unroll
    for (int mt = 0; mt < 2; ++mt)
        #pragma unroll
        for (int nt = 0; nt < 4; ++nt) {
            int o0 = w*32 + mt*16 + lk*4;
            int j  = nt*16 + lr;
            uint32_t u0 = __float_as_uint(fmaxf(acc1[mt][nt][0], 0.f));
            uint32_t u1 = __float_as_uint(fmaxf(acc1[mt][nt][1], 0.f));
            uint32_t u2 = __float_as_uint(fmaxf(acc1[mt][nt][2], 0.f));
            uint32_t u3 = __float_as_uint(fmaxf(acc1[mt][nt][3], 0.f));
            int us = eidx(j, o0);
            *(uint32_t*)&Ht[us]     = (u0 >> 16) | (u1 & 0xffff0000u);
            *(uint32_t*)&Ht[us + 2] = (u2 >> 16) | (u3 & 0xffff0000u);
        }
    __syncthreads();

    // ---- layer 2 ----
    f32x4 acc2[2][4];
    #pragma unroll
    for (int mt = 0; mt < 2; ++mt) {
        float4 bv = *(const float4*)(be2 + w*32 + mt*16 + lk*4);
        #pragma unroll
        for (int nt = 0; nt < 4; ++nt) {
            acc2[mt][nt][0] = bv.x; acc2[mt][nt][1] = bv.y;
            acc2[mt][nt][2] = bv.z; acc2[mt][nt][3] = bv.w;
        }
    }
    #pragma unroll
    for (int nt = 0; nt < 4; ++nt) {
        int j = nt*16 + lr;
        sh8 hh[4];
        #pragma unroll
        for (int ks = 0; ks < 4; ++ks)
            hh[ks] = *(const sh8*)&Ht[eidx(j, ks*32 + lk*8)];
        #pragma unroll
        for (int mt = 0; mt < 2; ++mt)
            #pragma unroll
            for (int ks = 0; ks < 4; ++ks)
                acc2[mt][nt] = MFMA_B16(A2[mt][ks], hh[ks], acc2[mt][nt]);
    }

    // ---- epilogue: edges1 = (Ehi+Elo) + ae0*relu(acc2), store PACKED ----
    #pragma unroll
    for (int mt = 0; mt < 2; ++mt) {
        int o0 = w*32 + mt*16 + lk*4;
        float4 a0v = *(const float4*)(ae0 + o0);
        float aev[4] = {a0v.x, a0v.y, a0v.z, a0v.w};
        #pragma unroll
        for (int nt = 0; nt < 4; ++nt) {
            int j = nt*16 + lr;
            int us = eidx(j, o0);
            sh4 eh = *(const sh4*)&Ehi[us];
            sh4 el = *(const sh4*)&Elo[us];
            #pragma unroll
            for (int r = 0; r < 4; ++r) {
                float e = bf2f((uint16_t)eh[r]) + bf2f((uint16_t)el[r]);
                float g = fmaxf(acc2[mt][nt][r], 0.f);
                e1out[(size_t)(b*CE_ + o0 + r)*SS_ + (size_t)i*S_ + j0 + j] =
                    pack_split(e + aev[r]*g);
            }
        }
    }
}

// ---------------- single-pass fused attention: qw + (stage|sim|online-softmax|se)x4 + nf ----------------
__global__ __launch_bounds__(256)
void k_attn(const uint32_t* __restrict__ e1, float* __restrict__ ws)
{
    __shared__ float Ef[128 * 67];     // f32 tile [c][j], stride 67 (bank-spread) 34304B
    __shared__ float qw[CE_ * 8];      // [c'][h] 4096B
    __shared__ float seA[8 * 128];     // [h][c'] unnormalized accum 4096B
    __shared__ float pL[8 * 64];       // [h][j]  sim -> p 2048B
    __shared__ float part[4 * 8 * 64]; // [cc][h][j] sim partials 8192B (qcol aliased below)
    __shared__ float mrow[8], srow[8], fh[8];
    float* qcol = part;                // alias: qcol used before part's first use

    const int t = threadIdx.x;
    const int b = blockIdx.x >> 8, i = blockIdx.x & 255;
    const float* maskf = ws + OFF_MASK;

    qcol[t] = ws[OFF_Q + (size_t)(b*AH_+t)*S_ + i];
    { // zero seA (4 each), init m/s
        #pragma unroll
        for (int r = 0; r < 4; ++r) seA[r*256 + t] = 0.f;
        if (t < 8) { mrow[t] = -3.4e38f; srow[t] = 0.f; fh[t] = 0.f; }
    }
    __syncthreads();

    { // qw phase: coalesced WkT[a][h][c] reads
        const float* WkT = ws + OFF_WKT;
        float q[4];
        #pragma unroll
        for (int k = 0; k < 4; ++k) {
            int idx = k*256 + t;
            int c = idx & 127, h = idx >> 7;  // h in 0..7 across k
            float acc = 0.f;
            #pragma unroll 8
            for (int aa = 0; aa < A_; ++aa)
                acc = fmaf(qcol[h*A_ + aa], WkT[aa*1024 + h*128 + c], acc);
            q[k] = acc;
        }
        __syncthreads();  // all qcol reads complete before part is later reused
        #pragma unroll
        for (int k = 0; k < 4; ++k) {
            int idx = k*256 + t;
            int c = idx & 127, h = idx >> 7;
            qw[c*8 + h] = q[k];
        }
    }
    __syncthreads();

    const uint32_t* Ebp = e1 + ((size_t)(b*CE_)*S_ + i)*S_;
    const int tj = t & 15;   // j-quad for staging
    const int tc = t >> 4;   // c-group for staging
    const int jj = t & 63;   // j for sim
    const int cc = t >> 6;   // c-chunk for sim

    for (int jt = 0; jt < 4; ++jt) {
        // ---- stage tile [c][j0..j0+63] -> Ef f32 ----
        #pragma unroll
        for (int s = 0; s < 8; ++s) {
            int c = s*16 + tc;
            uint4 v = *(const uint4*)(Ebp + (size_t)c*SS_ + jt*64 + tj*4);
            Ef[c*67 + tj*4 + 0] = unpack_f32(v.x);
            Ef[c*67 + tj*4 + 1] = unpack_f32(v.y);
            Ef[c*67 + tj*4 + 2] = unpack_f32(v.z);
            Ef[c*67 + tj*4 + 3] = unpack_f32(v.w);
        }
        __syncthreads();

        // ---- sim partials: thread (jj, cc): 32 c x 8 h ----
        {
            float s0=0,s1=0,s2=0,s3=0,s4=0,s5=0,s6=0,s7=0;
            for (int k = 0; k < 32; ++k) {
                int c = cc*32 + k;
                float e = Ef[c*67 + jj];
                float4 q0 = *(const float4*)(qw + c*8);
                float4 q1 = *(const float4*)(qw + c*8 + 4);
                s0 = fmaf(q0.x, e, s0); s1 = fmaf(q0.y, e, s1);
                s2 = fmaf(q0.z, e, s2); s3 = fmaf(q0.w, e, s3);
                s4 = fmaf(q1.x, e, s4); s5 = fmaf(q1.y, e, s5);
                s6 = fmaf(q1.z, e, s6); s7 = fmaf(q1.w, e, s7);
            }
            float* pp = part + cc*512 + jj;
            pp[0*64]=s0; pp[1*64]=s1; pp[2*64]=s2; pp[3*64]=s3;
            pp[4*64]=s4; pp[5*64]=s5; pp[6*64]=s6; pp[7*64]=s7;
        }
        __syncthreads();

        // ---- reduce partials + mask -> pL (raw sim) ----
        #pragma unroll
        for (int r = 0; r < 2; ++r) {
            int idx = r*256 + t;
            int h = idx >> 6, j = idx & 63;
            float sim = part[h*64 + j] + part[512 + h*64 + j]
                      + part[1024 + h*64 + j] + part[1536 + h*64 + j];
            float mj = maskf[b*S_ + jt*64 + j];
            pL[h*64 + j] = (mj != 0.f) ? sim : -1e9f;
        }
        __syncthreads();

        // ---- online softmax update (h = t>>5, l = t&31; 2 j per lane) ----
        {
            const int h = t >> 5, l = t & 31;
            float v0 = pL[h*64 + l], v1 = pL[h*64 + l + 32];
            float tm = fmaxf(v0, v1);
            #pragma unroll
            for (int off = 16; off >= 1; off >>= 1) tm = fmaxf(tm, __shfl_xor(tm, off, 32));
            float mold = mrow[h];
            float mnew = fmaxf(mold, tm);
            float e0 = __expf(v0 - mnew), e1v = __expf(v1 - mnew);
            float ts = e0 + e1v;
            #pragma unroll
            for (int off = 16; off >= 1; off >>= 1) ts += __shfl_xor(ts, off, 32);
            pL[h*64 + l] = e0; pL[h*64 + l + 32] = e1v;
            if (l == 0) {
                float f = __expf(mold - mnew);
                srow[h] = srow[h]*f + ts;
                mrow[h] = mnew;
                fh[h] = f;
            }
        }
        __syncthreads();

        // ---- seA accumulate: thread handles 4 (h,c') pairs ----
        #pragma unroll
        for (int r = 0; r < 4; ++r) {
            int idx = r*256 + t;
            int h = idx >> 7, cp = idx & 127;
            float acc = seA[idx] * fh[h];
            const float* er = Ef + cp*67;
            const float* pr = pL + h*64;
            #pragma unroll 8
            for (int j = 0; j < 64; ++j)
                acc = fmaf(pr[j], er[j], acc);
            seA[idx] = acc;
        }
        __syncthreads();  // protect Ef before next stage
    }

    { // nf phase: nf = vnode*mi + (Wv_edge @ se) with se = seA * mi/srow
        const int h2 = t >> 5;
        const float* WvT = ws + OFF_WVT;
        float acc = 0.f;
        for (int c = 0; c < CE_; ++c)
            acc = fmaf(WvT[c*256 + t], seA[h2*128 + c], acc);
        const float mi = maskf[b*S_ + i];
        float nfv = ws[OFF_VN + (size_t)(b*VH_+t)*S_ + i] * mi
                  + acc * (mi / srow[h2]);
        ws[OFF_NF + (size_t)(b*VH_+t)*S_ + i] = nfv;
    }
}

// ---------------- node output + Wnf, 4 cols/block ----------------
__global__ __launch_bounds__(256)
void k_node_out(float* __restrict__ ws, const float* __restrict__ Wo,
                const float* __restrict__ We, const float* __restrict__ an1,
                float* __restrict__ out_nodes)
{
    __shared__ float xs[VH_ * 4];
    const int t  = threadIdx.x;
    const int b  = blockIdx.x >> 6;
    const int s0 = (blockIdx.x & 63) * 4;
    {
        float4 nv = *(const float4*)(ws + OFF_NF + (size_t)(b*VH_+t)*S_ + s0);
        xs[t*4+0]=nv.x; xs[t*4+1]=nv.y; xs[t*4+2]=nv.z; xs[t*4+3]=nv.w;
    }
    __syncthreads();
    float a0=0.f, a1=0.f, a2=0.f, a3=0.f;
    GEMM4_K256(Wo + t*VH_, xs, a0, a1, a2, a3);
    {
        float aw = an1[t];
        float4 n1 = *(const float4*)(ws + OFF_N1 + (size_t)(b*CN_+t)*S_ + s0);
        float4 mk = *(const float4*)(ws + OFF_MASK + b*S_ + s0);
        *(float4*)(out_nodes + (size_t)(b*CN_+t)*S_ + s0) = make_float4(
            (n1.x + aw*a0) * mk.x, (n1.y + aw*a1) * mk.y,
            (n1.z + aw*a2) * mk.z, (n1.w + aw*a3) * mk.w);
    }
    if (t < CE_) { // Wnf = We[:, :VH] @ nf
        a0=0.f; a1=0.f; a2=0.f; a3=0.f;
        GEMM4_K256(We + t*CNE_, xs, a0, a1, a2, a3);
        *(float4*)(ws + OFF_WNF + (size_t)(b*CE_+t)*S_ + s0) = make_float4(a0,a1,a2,a3);
    }
}

// ---------------- edge output: hi-only MFMA (packed in, f32 out, in-place) ----------------
__global__ __launch_bounds__(256, 2)
void k_edge_out(const uint32_t* __restrict__ e1p, float* __restrict__ e1f,
                const float* __restrict__ ws, const float* __restrict__ ae1)
{
    __shared__ ushort Ehi[64 * 136];
    __shared__ ushort Elo[64 * 136];
    __shared__ float  wni_s[CE_];

    const int t  = threadIdx.x;
    const int b  = blockIdx.x >> 10;
    const int i  = (blockIdx.x >> 2) & 255;
    const int j0 = (blockIdx.x & 3) * 64;
    const uint32_t* Ebp = e1p + (size_t)b*CE_*SS_ + (size_t)i*S_ + j0;
    float*          Ebf = e1f + (size_t)b*CE_*SS_ + (size_t)i*S_ + j0;
    const float* Wnf   = ws + OFF_WNF;
    const float* maskf = ws + OFF_MASK;

    if (t < CE_) wni_s[t] = Wnf[(size_t)(b*CE_ + t)*S_ + i];

    // ---- stage: bit-split packed words into hi/lo LDS ----
    {
        const int tj = t & 15;
        const int p0 = t >> 4;
        #pragma unroll
        for (int s = 0; s < 4; ++s) {
            int c = (s*16 + p0) * 2;
            uint4 v0 = *(const uint4*)(Ebp + (size_t)c*SS_ + tj*4);
            uint4 v1 = *(const uint4*)(Ebp + (size_t)(c+1)*SS_ + tj*4);
            uint32_t w0[4] = {v0.x, v0.y, v0.z, v0.w};
            uint32_t w1[4] = {v1.x, v1.y, v1.z, v1.w};
            #pragma unroll
            for (int jj = 0; jj < 4; ++jj) {
                int j = tj*4 + jj;
                int us = eidx(j, c);
                *(uint32_t*)&Ehi[us] = (w0[jj] >> 16) | (w1[jj] & 0xffff0000u);
                *(uint32_t*)&Elo[us] = (w0[jj] & 0xffffu) | (w1[jj] << 16);
            }
        }
    }

    const int w  = t >> 6;
    const int l  = t & 63;
    const int lr = l & 15;
    const int lk = l >> 4;
    const ushort* wbe = (const ushort*)(ws + OFF_WBE);
    sh8 AE[2][4];
    #pragma unroll
    for (int mt = 0; mt < 2; ++mt) {
        int o = w*32 + mt*16 + lr;
        #pragma unroll
        for (int ks = 0; ks < 4; ++ks)
            AE[mt][ks] = *(const sh8*)(wbe + o*CE_ + ks*32 + lk*8);
    }

    f32x4 acc[2][4];
    #pragma unroll
    for (int mt = 0; mt < 2; ++mt)
        #pragma unroll
        for (int nt = 0; nt < 4; ++nt)
            acc[mt][nt] = (f32x4){0.f, 0.f, 0.f, 0.f};
    __syncthreads();
    #pragma unroll
    for (int nt = 0; nt < 4; ++nt) {
        int j = nt*16 + lr;
        sh8 bh[4];
        #pragma unroll
        for (int ks = 0; ks < 4; ++ks)
            bh[ks] = *(const sh8*)&Ehi[eidx(j, ks*32 + lk*8)];
        #pragma unroll
        for (int mt = 0; mt < 2; ++mt)
            #pragma unroll
            for (int ks = 0; ks < 4; ++ks)
                acc[mt][nt] = MFMA_B16(AE[mt][ks], bh[ks], acc[mt][nt]);
    }

    // ---- epilogue ----
    const float mi = maskf[b*S_ + i];
    #pragma unroll
    for (int mt = 0; mt < 2; ++mt) {
        int o0 = w*32 + mt*16 + lk*4;
        float4 a1v = *(const float4*)(ae1 + o0);
        float aev[4] = {a1v.x, a1v.y, a1v.z, a1v.w};
        #pragma unroll
        for (int nt = 0; nt < 4; ++nt) {
            int j  = nt*16 + lr;
            int jg = j0 + j;
            float mjv = maskf[b*S_ + jg];
            int us = eidx(j, o0);
            sh4 eh = *(const sh4*)&Ehi[us];
            sh4 el = *(const sh4*)&Elo[us];
            #pragma unroll
            for (int r = 0; r < 4; ++r) {
                float e   = bf2f((uint16_t)eh[r]) + bf2f((uint16_t)el[r]);
                float att = 0.5f*(wni_s[o0+r] + Wnf[(size_t)(b*CE_+o0+r)*S_ + jg])
                          + acc[mt][nt][r];
                Ebf[(size_t)(o0+r)*SS_ + j] = (e + aev[r]*att) * (mi * mjv);
            }
        }
    }
}

// ---------------- launch ----------------
extern "C" void kernel_launch(void* const* d_in, const int* in_sizes, int n_in,
                              void* d_out, int out_size, void* d_ws, size_t ws_size,
                              hipStream_t stream)
{
    const float* nodes = (const float*)d_in[0];
    const float* edges = (const float*)d_in[1];
    const unsigned char* mraw = (const unsigned char*)d_in[2];
    const float* Wq  = (const float*)d_in[3];
    const float* Wk  = (const float*)d_in[4];
    const float* Wv  = (const float*)d_in[5];
    const float* Wo  = (const float*)d_in[6];
    const float* We  = (const float*)d_in[7];
    const float* Wm1 = (const float*)d_in[8];
    const float* bm1 = (const float*)d_in[9];
    const float* Wm2 = (const float*)d_in[10];
    const float* bm2 = (const float*)d_in[11];
    const float* We1 = (const float*)d_in[12];
    const float* be1 = (const float*)d_in[13];
    const float* We2 = (const float*)d_in[14];
    const float* be2 = (const float*)d_in[15];
    const float* an0 = (const float*)d_in[16];
    const float* an1 = (const float*)d_in[17];
    const float* ae0 = (const float*)d_in[18];
    const float* ae1 = (const float*)d_in[19];

    float* ws = (float*)d_ws;
    float* out_nodes = (float*)d_out;
    float* out_edges = out_nodes + (size_t)B_*CN_*S_; // packed during pipeline, f32 at end

    k_mask_norm  <<<1,    512, 0, stream>>>(mraw, ws);
    k_wprep      <<<448,  256, 0, stream>>>(We1, We2, We, Wk, Wv, ws);
    k_node_mlp_qv<<<128,  256, 0, stream>>>(nodes, Wm1, bm1, Wm2, bm2, an0, Wq, Wv, ws);
    k_edge_mlp   <<<2048, 256, 0, stream>>>(edges, ws, be1, be2, ae0, (uint32_t*)out_edges);
    k_attn       <<<512,  256, 0, stream>>>((const uint32_t*)out_edges, ws);
    k_node_out   <<<128,  256, 0, stream>>>(ws, Wo, We, an1, out_nodes);
    k_edge_out   <<<2048, 256, 0, stream>>>((const uint32_t*)out_edges, out_edges, ws, ae1);
}